// Round 7
// baseline (1173.962 us; speedup 1.0000x reference)
//
#include <hip/hip_runtime.h>
#include <stdint.h>

#define H 128
#define H2 256
#define NLAYERS 4
#define BN_EPS 1e-5f

// CSR bucketing
#define BSHIFT 10
#define NPB 1024
#define NBC 98
#define PART_BATCH 2048
#define EPT 8

typedef __attribute__((ext_vector_type(4))) float f32x4;
typedef __attribute__((ext_vector_type(8))) short bhalf8;

__device__ __forceinline__ float bf2f(unsigned short u) {
    union { unsigned int i; float f; } v;
    v.i = ((unsigned int)u) << 16;
    return v.f;
}
__device__ __forceinline__ unsigned short f2bf(float f) {
    union { float f; unsigned int i; } v;
    v.f = f;
    unsigned int b = v.i + 0x7FFFu + ((v.i >> 16) & 1u);
    return (unsigned short)(b >> 16);
}

// ---------------- embedding: h = x @ Wemb + bemb  (bf16 out) ----------------
__global__ __launch_bounds__(256) void embed_kernel(
    const float* __restrict__ x, const float* __restrict__ Wemb,
    const float* __restrict__ bemb, unsigned short* __restrict__ h, int N) {
    int n = blockIdx.x * 2 + (threadIdx.x >> 7);
    int f = threadIdx.x & 127;
    if (n >= N) return;
    const float* xr = x + (size_t)n * 9;
    float acc = bemb[f];
#pragma unroll
    for (int k = 0; k < 9; k++) acc += xr[k] * Wemb[k * H + f];
    h[(size_t)n * H + f] = f2bf(acc);
}

// ---------------- BN param fold ----------------
__global__ void prep_params(
    const float* __restrict__ b1, const float* __restrict__ g1, const float* __restrict__ be1,
    const float* __restrict__ m1, const float* __restrict__ v1,
    const float* __restrict__ b2, const float* __restrict__ g2, const float* __restrict__ be2,
    const float* __restrict__ m2, const float* __restrict__ v2,
    float* __restrict__ sc1, float* __restrict__ sh1,
    float* __restrict__ sc2, float* __restrict__ sh2) {
    int t = threadIdx.x;  // 1024 threads
    if (t < NLAYERS * H2) {
        float s = g1[t] * rsqrtf(v1[t] + BN_EPS);
        sc1[t] = s;
        sh1[t] = (b1[t] - m1[t]) * s + be1[t];
    }
    if (t < NLAYERS * H) {
        float s = g2[t] * rsqrtf(v2[t] + BN_EPS);
        sc2[t] = s;
        sh2[t] = (b2[t] - m2[t]) * s + be2[t];
    }
}

// ---------------- weight transpose + bf16 convert ----------------
__global__ __launch_bounds__(256) void prep_weights(
    const float* __restrict__ W1, const float* __restrict__ W2,
    unsigned short* __restrict__ W1T, unsigned short* __restrict__ W2T) {
    int idx = blockIdx.x * 256 + threadIdx.x;
    if (idx >= NLAYERS * H * H2) return;
    int l = idx >> 15;
    {
        int r = idx & 32767;
        int c = r >> 7, k = r & 127;
        W1T[idx] = f2bf(W1[((size_t)l * H + k) * H2 + c]);
    }
    {
        int r = idx & 32767;
        int c = r >> 8, k = r & 255;
        W2T[idx] = f2bf(W2[((size_t)l * H2 + k) * H + c]);
    }
}

// ---------------- CSR build (bucketed, write-locality-aware) ----------------
__global__ __launch_bounds__(256) void hist_coarse(const int* __restrict__ ei,
                                                   unsigned* __restrict__ bc_cnt,
                                                   int E, int nbc) {
    __shared__ unsigned lh[NBC];
    for (int i = threadIdx.x; i < nbc; i += 256) lh[i] = 0;
    __syncthreads();
    for (int e = blockIdx.x * 256 + threadIdx.x; e < E; e += gridDim.x * 256)
        atomicAdd(&lh[(unsigned)ei[E + e] >> BSHIFT], 1u);
    __syncthreads();
    for (int i = threadIdx.x; i < nbc; i += 256)
        if (lh[i]) atomicAdd(&bc_cnt[i], lh[i]);
}

__global__ __launch_bounds__(128) void scan_coarse(const unsigned* __restrict__ bc_cnt,
                                                   unsigned* __restrict__ bc_base,
                                                   unsigned* __restrict__ bc_cursor,
                                                   int nbc, int E) {
    __shared__ unsigned sd[128];
    int t = threadIdx.x;
    unsigned v = (t < nbc) ? bc_cnt[t] : 0u;
    sd[t] = v;
    __syncthreads();
    for (int off = 1; off < 128; off <<= 1) {
        unsigned xv = (t >= off) ? sd[t - off] : 0u;
        __syncthreads();
        sd[t] += xv;
        __syncthreads();
    }
    unsigned excl = sd[t] - v;
    if (t < nbc) {
        bc_base[t] = excl;
        bc_cursor[t] = excl;
    }
    if (t == 0) bc_base[nbc] = (unsigned)E;
}

__global__ __launch_bounds__(256) void partition_kernel(const int* __restrict__ ei,
                                                        unsigned* __restrict__ bc_cursor,
                                                        uint2* __restrict__ part,
                                                        int E, int nbc) {
    __shared__ unsigned lh[NBC];
    __shared__ unsigned lb[NBC];
    for (int i = threadIdx.x; i < nbc; i += 256) lh[i] = 0;
    __syncthreads();
    int base = blockIdx.x * PART_BATCH;
    int s[EPT], d[EPT];
    unsigned rank[EPT];
    int bk[EPT];
#pragma unroll
    for (int k = 0; k < EPT; k++) {
        int e = base + k * 256 + threadIdx.x;
        if (e < E) {
            s[k] = ei[e];
            d[k] = ei[E + e];
            bk[k] = (unsigned)d[k] >> BSHIFT;
            rank[k] = atomicAdd(&lh[bk[k]], 1u);
        } else bk[k] = -1;
    }
    __syncthreads();
    for (int i = threadIdx.x; i < nbc; i += 256)
        lb[i] = lh[i] ? atomicAdd(&bc_cursor[i], lh[i]) : 0u;
    __syncthreads();
#pragma unroll
    for (int k = 0; k < EPT; k++) {
        if (bk[k] >= 0) {
            unsigned p = lb[bk[k]] + rank[k];
            part[p] = make_uint2((unsigned)s[k], (unsigned)d[k]);
        }
    }
}

__global__ __launch_bounds__(1024) void bucket_degrees(const uint2* __restrict__ part,
                                                       const unsigned* __restrict__ bc_base,
                                                       unsigned* __restrict__ gdeg, int N) {
    __shared__ unsigned deg[NPB];
    int b = blockIdx.x;
    deg[threadIdx.x] = 0;
    __syncthreads();
    unsigned r0 = bc_base[b], r1 = bc_base[b + 1];
    for (unsigned i = r0 + threadIdx.x; i < r1; i += 1024)
        atomicAdd(&deg[part[i].y & (NPB - 1)], 1u);
    __syncthreads();
    int node = (b << BSHIFT) + threadIdx.x;
    if (node < N) gdeg[node] = deg[threadIdx.x];
}

__global__ __launch_bounds__(256) void scanA_kernel(const unsigned* __restrict__ deg,
                                                    unsigned* __restrict__ rowptr,
                                                    unsigned* __restrict__ bsum, int N) {
    __shared__ unsigned sd[256];
    int tid = threadIdx.x;
    int base = blockIdx.x * 1024 + tid * 4;
    unsigned v[4];
    unsigned s = 0;
#pragma unroll
    for (int j = 0; j < 4; j++) {
        v[j] = (base + j < N) ? deg[base + j] : 0u;
        s += v[j];
    }
    sd[tid] = s;
    __syncthreads();
    for (int off = 1; off < 256; off <<= 1) {
        unsigned xv = (tid >= off) ? sd[tid - off] : 0u;
        __syncthreads();
        sd[tid] += xv;
        __syncthreads();
    }
    unsigned excl = sd[tid] - s;
#pragma unroll
    for (int j = 0; j < 4; j++) {
        if (base + j < N) rowptr[base + j] = excl;
        excl += v[j];
    }
    if (tid == 255) bsum[blockIdx.x] = sd[255];
}

__global__ __launch_bounds__(1024) void scanB_kernel(unsigned* __restrict__ bsum, int nb) {
    __shared__ unsigned sd[1024];
    int t = threadIdx.x;
    unsigned s = (t < nb) ? bsum[t] : 0u;
    sd[t] = s;
    __syncthreads();
    for (int off = 1; off < 1024; off <<= 1) {
        unsigned xv = (t >= off) ? sd[t - off] : 0u;
        __syncthreads();
        sd[t] += xv;
        __syncthreads();
    }
    if (t < nb) bsum[t] = sd[t] - s;
}

__global__ __launch_bounds__(256) void scanC_kernel(unsigned* __restrict__ rowptr,
                                                    const unsigned* __restrict__ bsum,
                                                    int N, int E) {
    int base = blockIdx.x * 1024 + threadIdx.x * 4;
    unsigned off = bsum[blockIdx.x];
#pragma unroll
    for (int j = 0; j < 4; j++) {
        int i = base + j;
        if (i < N) rowptr[i] += off;
    }
    if (blockIdx.x == 0 && threadIdx.x == 0) rowptr[N] = (unsigned)E;
}

__global__ __launch_bounds__(1024) void bucket_fill(const uint2* __restrict__ part,
                                                    const unsigned* __restrict__ bc_base,
                                                    const unsigned* __restrict__ rowptr,
                                                    unsigned* __restrict__ col, int N) {
    __shared__ unsigned cur[NPB];
    int b = blockIdx.x;
    int node = (b << BSHIFT) + threadIdx.x;
    cur[threadIdx.x] = (node < N) ? rowptr[node] : 0u;
    __syncthreads();
    unsigned r0 = bc_base[b], r1 = bc_base[b + 1];
    for (unsigned i = r0 + threadIdx.x; i < r1; i += 1024) {
        uint2 e = part[i];
        unsigned p = atomicAdd(&cur[e.y & (NPB - 1)], 1u);
        col[p] = e.x;
    }
}

// ---------------- aggregation: z = (1+eps)*h + sum_{neigh} h ----------------
__global__ __launch_bounds__(128) void agg_kernel(
    const unsigned short* __restrict__ h, const unsigned* __restrict__ rowptr,
    const unsigned* __restrict__ col, const float* __restrict__ eps, int layer,
    unsigned short* __restrict__ z, int N) {
    int n = blockIdx.x * 2 + (threadIdx.x >> 6);
    if (n >= N) return;
    int lane = threadIdx.x & 63;
    int chunk = lane & 15;
    int sub = lane >> 4;
    unsigned r0 = rowptr[n], r1 = rowptr[n + 1];
    float acc0[8], acc1[8];
#pragma unroll
    for (int k = 0; k < 8; k++) { acc0[k] = 0.f; acc1[k] = 0.f; }
    unsigned j = r0 + sub;
    for (; j + 4 < r1; j += 8) {
        unsigned c0 = col[j], c1 = col[j + 4];
        bhalf8 v0 = *(const bhalf8*)&h[(size_t)c0 * H + chunk * 8];
        bhalf8 v1 = *(const bhalf8*)&h[(size_t)c1 * H + chunk * 8];
#pragma unroll
        for (int k = 0; k < 8; k++) {
            acc0[k] += bf2f((unsigned short)v0[k]);
            acc1[k] += bf2f((unsigned short)v1[k]);
        }
    }
    if (j < r1) {
        unsigned c0 = col[j];
        bhalf8 v0 = *(const bhalf8*)&h[(size_t)c0 * H + chunk * 8];
#pragma unroll
        for (int k = 0; k < 8; k++) acc0[k] += bf2f((unsigned short)v0[k]);
    }
#pragma unroll
    for (int k = 0; k < 8; k++) {
        acc0[k] += acc1[k];
        acc0[k] += __shfl_xor(acc0[k], 16, 64);
        acc0[k] += __shfl_xor(acc0[k], 32, 64);
    }
    if (sub == 0) {
        float e = 1.0f + eps[layer];
        bhalf8 hv = *(const bhalf8*)&h[(size_t)n * H + chunk * 8];
        bhalf8 o;
#pragma unroll
        for (int k = 0; k < 8; k++)
            o[k] = (short)f2bf(e * bf2f((unsigned short)hv[k]) + acc0[k]);
        *(bhalf8*)&z[(size_t)n * H + chunk * 8] = o;
    }
}

// ---------------- MLP1: t = relu(bn1(z @ W1 + b1))  [N,256] ----------------
// No LDS: weights (64 KB) stay L1/L2-resident. Wave computes 64 rows x 64 cols
// (4 row-blocks x 4 col-blocks, 4x B-reuse); 4 waves cover 64 rows x 256 cols.
__global__ __launch_bounds__(256) void mlp1_kernel(
    const unsigned short* __restrict__ z, const unsigned short* __restrict__ W1T,
    const float* __restrict__ sc1, const float* __restrict__ sh1,
    unsigned short* __restrict__ t, int N) {
    int wave = threadIdx.x >> 6, lane = threadIdx.x & 63;
    int rtile = blockIdx.x * 64;
    int wcol = wave * 64;
    int rlane = lane & 15;
    int kg = (lane >> 4) * 8;
    int arow[4];
#pragma unroll
    for (int rb = 0; rb < 4; rb++) {
        int r = rtile + rb * 16 + rlane;
        arow[rb] = r < N ? r : N - 1;
    }
    f32x4 zero = {0.f, 0.f, 0.f, 0.f};
    f32x4 acc[4][4];
#pragma unroll
    for (int rb = 0; rb < 4; rb++)
#pragma unroll
        for (int cb = 0; cb < 4; cb++) acc[rb][cb] = zero;
#pragma unroll
    for (int ks = 0; ks < 4; ks++) {
        bhalf8 a[4], b[4];
#pragma unroll
        for (int rb = 0; rb < 4; rb++)
            a[rb] = *(const bhalf8*)&z[(size_t)arow[rb] * H + ks * 32 + kg];
#pragma unroll
        for (int cb = 0; cb < 4; cb++)
            b[cb] = *(const bhalf8*)&W1T[(size_t)(wcol + cb * 16 + rlane) * H + ks * 32 + kg];
#pragma unroll
        for (int rb = 0; rb < 4; rb++)
#pragma unroll
            for (int cb = 0; cb < 4; cb++)
                acc[rb][cb] = __builtin_amdgcn_mfma_f32_16x16x32_bf16(a[rb], b[cb], acc[rb][cb], 0, 0, 0);
    }
    int rr = rtile + ((lane >> 4) << 2);
#pragma unroll
    for (int cb = 0; cb < 4; cb++) {
        int colc = wcol + cb * 16 + rlane;
        float sc = sc1[colc], sh = sh1[colc];
#pragma unroll
        for (int rb = 0; rb < 4; rb++) {
#pragma unroll
            for (int j = 0; j < 4; j++) {
                int row = rr + rb * 16 + j;
                if (row < N) {
                    float vv = acc[rb][cb][j] * sc + sh;
                    vv = vv > 0.f ? vv : 0.f;
                    t[(size_t)row * H2 + colc] = f2bf(vv);
                }
            }
        }
    }
}

// ---------------- MLP2: h = relu(bn2(t @ W2 + b2))  [N,128] ----------------
// Wave computes 64 rows x 32 cols; 4 waves cover 64 rows x 128 cols.
__global__ __launch_bounds__(256) void mlp2_kernel(
    const unsigned short* __restrict__ t, const unsigned short* __restrict__ W2T,
    const float* __restrict__ sc2, const float* __restrict__ sh2,
    unsigned short* __restrict__ h, int N) {
    int wave = threadIdx.x >> 6, lane = threadIdx.x & 63;
    int rtile = blockIdx.x * 64;
    int wcol = wave * 32;
    int rlane = lane & 15;
    int kg = (lane >> 4) * 8;
    int arow[4];
#pragma unroll
    for (int rb = 0; rb < 4; rb++) {
        int r = rtile + rb * 16 + rlane;
        arow[rb] = r < N ? r : N - 1;
    }
    f32x4 zero = {0.f, 0.f, 0.f, 0.f};
    f32x4 acc[4][2];
#pragma unroll
    for (int rb = 0; rb < 4; rb++)
#pragma unroll
        for (int cb = 0; cb < 2; cb++) acc[rb][cb] = zero;
#pragma unroll
    for (int ks = 0; ks < 8; ks++) {
        bhalf8 a[4], b[2];
#pragma unroll
        for (int rb = 0; rb < 4; rb++)
            a[rb] = *(const bhalf8*)&t[(size_t)arow[rb] * H2 + ks * 32 + kg];
#pragma unroll
        for (int cb = 0; cb < 2; cb++)
            b[cb] = *(const bhalf8*)&W2T[(size_t)(wcol + cb * 16 + rlane) * H2 + ks * 32 + kg];
#pragma unroll
        for (int rb = 0; rb < 4; rb++)
#pragma unroll
            for (int cb = 0; cb < 2; cb++)
                acc[rb][cb] = __builtin_amdgcn_mfma_f32_16x16x32_bf16(a[rb], b[cb], acc[rb][cb], 0, 0, 0);
    }
    int rr = rtile + ((lane >> 4) << 2);
#pragma unroll
    for (int cb = 0; cb < 2; cb++) {
        int colc = wcol + cb * 16 + rlane;
        float sc = sc2[colc], sh = sh2[colc];
#pragma unroll
        for (int rb = 0; rb < 4; rb++) {
#pragma unroll
            for (int j = 0; j < 4; j++) {
                int row = rr + rb * 16 + j;
                if (row < N) {
                    float vv = acc[rb][cb][j] * sc + sh;
                    vv = vv > 0.f ? vv : 0.f;
                    h[(size_t)row * H + colc] = f2bf(vv);
                }
            }
        }
    }
}

// ---------------- global mean pool ----------------
__global__ __launch_bounds__(128) void pool_kernel(
    const unsigned short* __restrict__ h, const int* __restrict__ batch,
    float* __restrict__ out, int N, int G) {
    __shared__ int se[2];
    int g = blockIdx.x;
    if (threadIdx.x == 0) {
        int lo = 0, hi = N;
        while (lo < hi) {
            int mid = (lo + hi) >> 1;
            if (batch[mid] < g) lo = mid + 1; else hi = mid;
        }
        se[0] = lo;
        hi = N;
        while (lo < hi) {
            int mid = (lo + hi) >> 1;
            if (batch[mid] < g + 1) lo = mid + 1; else hi = mid;
        }
        se[1] = lo;
    }
    __syncthreads();
    int s = se[0], e = se[1];
    int f = threadIdx.x;
    float acc = 0.f;
    for (int r = s; r < e; ++r) acc += bf2f(h[(size_t)r * H + f]);
    int cnt = e - s;
    out[(size_t)g * H + f] = cnt > 0 ? acc / (float)cnt : 0.f;
}

// ---------------- launch ----------------
extern "C" void kernel_launch(void* const* d_in, const int* in_sizes, int n_in,
                              void* d_out, int out_size, void* d_ws, size_t ws_size,
                              hipStream_t stream) {
    const float* x     = (const float*)d_in[0];
    const int*   ei    = (const int*)d_in[1];
    const int*   batch = (const int*)d_in[2];
    const float* Wemb  = (const float*)d_in[3];
    const float* bemb  = (const float*)d_in[4];
    const float* eps   = (const float*)d_in[5];
    const float* W1    = (const float*)d_in[6];
    const float* b1    = (const float*)d_in[7];
    const float* g1    = (const float*)d_in[8];
    const float* be1   = (const float*)d_in[9];
    const float* m1    = (const float*)d_in[10];
    const float* v1    = (const float*)d_in[11];
    const float* W2    = (const float*)d_in[12];
    const float* b2    = (const float*)d_in[13];
    const float* g2    = (const float*)d_in[14];
    const float* be2   = (const float*)d_in[15];
    const float* m2    = (const float*)d_in[16];
    const float* v2    = (const float*)d_in[17];

    int N = in_sizes[0] / 9;
    int E = in_sizes[1] / 2;
    int G = out_size / H;
    int nbc = (N + NPB - 1) >> BSHIFT;

    char* p = (char*)d_ws;
    auto alloc = [&](size_t bytes) -> char* {
        char* r = p;
        p += (bytes + 255) & ~(size_t)255;
        return r;
    };
    unsigned short* h   = (unsigned short*)alloc((size_t)N * H * 2);
    unsigned short* z   = (unsigned short*)alloc((size_t)N * H * 2);
    unsigned short* t   = (unsigned short*)alloc((size_t)N * H2 * 2);
    unsigned*       rowptr = (unsigned*)alloc((size_t)(N + 1) * 4);
    unsigned*       gdeg   = (unsigned*)alloc((size_t)N * 4);
    unsigned*       bsum   = (unsigned*)alloc(1024 * 4);
    unsigned*       col    = (unsigned*)alloc((size_t)E * 4);
    unsigned short* W1T = (unsigned short*)alloc((size_t)NLAYERS * H * H2 * 2);
    unsigned short* W2T = (unsigned short*)alloc((size_t)NLAYERS * H * H2 * 2);
    float* sc1 = (float*)alloc(NLAYERS * H2 * 4);
    float* sh1 = (float*)alloc(NLAYERS * H2 * 4);
    float* sc2 = (float*)alloc(NLAYERS * H * 4);
    float* sh2 = (float*)alloc(NLAYERS * H * 4);
    unsigned* bc_cnt    = (unsigned*)alloc((NBC + 2) * 4);
    unsigned* bc_base   = (unsigned*)alloc((NBC + 2) * 4);
    unsigned* bc_cursor = (unsigned*)alloc((NBC + 2) * 4);
    uint2* part = (uint2*)t;  // alias: t unused until layer loop

    hipMemsetAsync(bc_cnt, 0, (NBC + 2) * 4, stream);
    prep_params<<<1, 1024, 0, stream>>>(b1, g1, be1, m1, v1, b2, g2, be2, m2, v2,
                                        sc1, sh1, sc2, sh2);
    prep_weights<<<(NLAYERS * H * H2 + 255) / 256, 256, 0, stream>>>(W1, W2, W1T, W2T);
    embed_kernel<<<(N + 1) / 2, 256, 0, stream>>>(x, Wemb, bemb, h, N);

    // CSR build
    hist_coarse<<<512, 256, 0, stream>>>(ei, bc_cnt, E, nbc);
    scan_coarse<<<1, 128, 0, stream>>>(bc_cnt, bc_base, bc_cursor, nbc, E);
    partition_kernel<<<(E + PART_BATCH - 1) / PART_BATCH, 256, 0, stream>>>(
        ei, bc_cursor, part, E, nbc);
    bucket_degrees<<<nbc, 1024, 0, stream>>>(part, bc_base, gdeg, N);
    int nb = (N + 1023) / 1024;
    scanA_kernel<<<nb, 256, 0, stream>>>(gdeg, rowptr, bsum, N);
    scanB_kernel<<<1, 1024, 0, stream>>>(bsum, nb);
    scanC_kernel<<<nb, 256, 0, stream>>>(rowptr, bsum, N, E);
    bucket_fill<<<nbc, 1024, 0, stream>>>(part, bc_base, rowptr, col, N);

    for (int l = 0; l < NLAYERS; l++) {
        agg_kernel<<<(N + 1) / 2, 128, 0, stream>>>(h, rowptr, col, eps, l, z, N);
        mlp1_kernel<<<(N + 63) / 64, 256, 0, stream>>>(z, W1T + (size_t)l * H * H2,
                                                       sc1 + l * H2, sh1 + l * H2, t, N);
        mlp2_kernel<<<(N + 63) / 64, 256, 0, stream>>>(t, W2T + (size_t)l * H * H2,
                                                       sc2 + l * H, sh2 + l * H, h, N);
    }
    pool_kernel<<<G, 128, 0, stream>>>(h, batch, (float*)d_out, N, G);
}

// Round 9
// 965.133 us; speedup vs baseline: 1.2164x; 1.2164x over previous
//
#include <hip/hip_runtime.h>
#include <stdint.h>

#define H 128
#define H2 256
#define NLAYERS 4
#define BN_EPS 1e-5f

// CSR bucketing
#define BSHIFT 10
#define NPB 1024
#define NBC 98
#define PART_BATCH 2048
#define EPT 8

typedef __attribute__((ext_vector_type(4))) float f32x4;
typedef __attribute__((ext_vector_type(8))) short bhalf8;

__device__ __forceinline__ float bf2f(unsigned short u) {
    union { unsigned int i; float f; } v;
    v.i = ((unsigned int)u) << 16;
    return v.f;
}
__device__ __forceinline__ unsigned short f2bf(float f) {
    union { float f; unsigned int i; } v;
    v.f = f;
    unsigned int b = v.i + 0x7FFFu + ((v.i >> 16) & 1u);
    return (unsigned short)(b >> 16);
}

// ---------------- embedding: h = x @ Wemb + bemb  (bf16 out) ----------------
__global__ __launch_bounds__(256) void embed_kernel(
    const float* __restrict__ x, const float* __restrict__ Wemb,
    const float* __restrict__ bemb, unsigned short* __restrict__ h, int N) {
    int n = blockIdx.x * 2 + (threadIdx.x >> 7);
    int f = threadIdx.x & 127;
    if (n >= N) return;
    const float* xr = x + (size_t)n * 9;
    float acc = bemb[f];
#pragma unroll
    for (int k = 0; k < 9; k++) acc += xr[k] * Wemb[k * H + f];
    h[(size_t)n * H + f] = f2bf(acc);
}

// ---------------- BN param fold ----------------
__global__ void prep_params(
    const float* __restrict__ b1, const float* __restrict__ g1, const float* __restrict__ be1,
    const float* __restrict__ m1, const float* __restrict__ v1,
    const float* __restrict__ b2, const float* __restrict__ g2, const float* __restrict__ be2,
    const float* __restrict__ m2, const float* __restrict__ v2,
    float* __restrict__ sc1, float* __restrict__ sh1,
    float* __restrict__ sc2, float* __restrict__ sh2) {
    int t = threadIdx.x;  // 1024 threads
    if (t < NLAYERS * H2) {
        float s = g1[t] * rsqrtf(v1[t] + BN_EPS);
        sc1[t] = s;
        sh1[t] = (b1[t] - m1[t]) * s + be1[t];
    }
    if (t < NLAYERS * H) {
        float s = g2[t] * rsqrtf(v2[t] + BN_EPS);
        sc2[t] = s;
        sh2[t] = (b2[t] - m2[t]) * s + be2[t];
    }
}

// ---------------- weight transpose + bf16 convert ----------------
__global__ __launch_bounds__(256) void prep_weights(
    const float* __restrict__ W1, const float* __restrict__ W2,
    unsigned short* __restrict__ W1T, unsigned short* __restrict__ W2T) {
    int idx = blockIdx.x * 256 + threadIdx.x;
    if (idx >= NLAYERS * H * H2) return;
    int l = idx >> 15;
    {
        int r = idx & 32767;
        int c = r >> 7, k = r & 127;
        W1T[idx] = f2bf(W1[((size_t)l * H + k) * H2 + c]);
    }
    {
        int r = idx & 32767;
        int c = r >> 8, k = r & 255;
        W2T[idx] = f2bf(W2[((size_t)l * H2 + k) * H + c]);
    }
}

// ---------------- CSR build (bucketed, write-locality-aware) ----------------
__global__ __launch_bounds__(256) void hist_coarse(const int* __restrict__ ei,
                                                   unsigned* __restrict__ bc_cnt,
                                                   int E, int nbc) {
    __shared__ unsigned lh[NBC];
    for (int i = threadIdx.x; i < nbc; i += 256) lh[i] = 0;
    __syncthreads();
    for (int e = blockIdx.x * 256 + threadIdx.x; e < E; e += gridDim.x * 256)
        atomicAdd(&lh[(unsigned)ei[E + e] >> BSHIFT], 1u);
    __syncthreads();
    for (int i = threadIdx.x; i < nbc; i += 256)
        if (lh[i]) atomicAdd(&bc_cnt[i], lh[i]);
}

__global__ __launch_bounds__(128) void scan_coarse(const unsigned* __restrict__ bc_cnt,
                                                   unsigned* __restrict__ bc_base,
                                                   unsigned* __restrict__ bc_cursor,
                                                   int nbc, int E) {
    __shared__ unsigned sd[128];
    int t = threadIdx.x;
    unsigned v = (t < nbc) ? bc_cnt[t] : 0u;
    sd[t] = v;
    __syncthreads();
    for (int off = 1; off < 128; off <<= 1) {
        unsigned xv = (t >= off) ? sd[t - off] : 0u;
        __syncthreads();
        sd[t] += xv;
        __syncthreads();
    }
    unsigned excl = sd[t] - v;
    if (t < nbc) {
        bc_base[t] = excl;
        bc_cursor[t] = excl;
    }
    if (t == 0) bc_base[nbc] = (unsigned)E;
}

__global__ __launch_bounds__(256) void partition_kernel(const int* __restrict__ ei,
                                                        unsigned* __restrict__ bc_cursor,
                                                        uint2* __restrict__ part,
                                                        int E, int nbc) {
    __shared__ unsigned lh[NBC];
    __shared__ unsigned lb[NBC];
    for (int i = threadIdx.x; i < nbc; i += 256) lh[i] = 0;
    __syncthreads();
    int base = blockIdx.x * PART_BATCH;
    int s[EPT], d[EPT];
    unsigned rank[EPT];
    int bk[EPT];
#pragma unroll
    for (int k = 0; k < EPT; k++) {
        int e = base + k * 256 + threadIdx.x;
        if (e < E) {
            s[k] = ei[e];
            d[k] = ei[E + e];
            bk[k] = (unsigned)d[k] >> BSHIFT;
            rank[k] = atomicAdd(&lh[bk[k]], 1u);
        } else bk[k] = -1;
    }
    __syncthreads();
    for (int i = threadIdx.x; i < nbc; i += 256)
        lb[i] = lh[i] ? atomicAdd(&bc_cursor[i], lh[i]) : 0u;
    __syncthreads();
#pragma unroll
    for (int k = 0; k < EPT; k++) {
        if (bk[k] >= 0) {
            unsigned p = lb[bk[k]] + rank[k];
            part[p] = make_uint2((unsigned)s[k], (unsigned)d[k]);
        }
    }
}

__global__ __launch_bounds__(1024) void bucket_degrees(const uint2* __restrict__ part,
                                                       const unsigned* __restrict__ bc_base,
                                                       unsigned* __restrict__ gdeg, int N) {
    __shared__ unsigned deg[NPB];
    int b = blockIdx.x;
    deg[threadIdx.x] = 0;
    __syncthreads();
    unsigned r0 = bc_base[b], r1 = bc_base[b + 1];
    for (unsigned i = r0 + threadIdx.x; i < r1; i += 1024)
        atomicAdd(&deg[part[i].y & (NPB - 1)], 1u);
    __syncthreads();
    int node = (b << BSHIFT) + threadIdx.x;
    if (node < N) gdeg[node] = deg[threadIdx.x];
}

__global__ __launch_bounds__(256) void scanA_kernel(const unsigned* __restrict__ deg,
                                                    unsigned* __restrict__ rowptr,
                                                    unsigned* __restrict__ bsum, int N) {
    __shared__ unsigned sd[256];
    int tid = threadIdx.x;
    int base = blockIdx.x * 1024 + tid * 4;
    unsigned v[4];
    unsigned s = 0;
#pragma unroll
    for (int j = 0; j < 4; j++) {
        v[j] = (base + j < N) ? deg[base + j] : 0u;
        s += v[j];
    }
    sd[tid] = s;
    __syncthreads();
    for (int off = 1; off < 256; off <<= 1) {
        unsigned xv = (tid >= off) ? sd[tid - off] : 0u;
        __syncthreads();
        sd[tid] += xv;
        __syncthreads();
    }
    unsigned excl = sd[tid] - s;
#pragma unroll
    for (int j = 0; j < 4; j++) {
        if (base + j < N) rowptr[base + j] = excl;
        excl += v[j];
    }
    if (tid == 255) bsum[blockIdx.x] = sd[255];
}

__global__ __launch_bounds__(1024) void scanB_kernel(unsigned* __restrict__ bsum, int nb) {
    __shared__ unsigned sd[1024];
    int t = threadIdx.x;
    unsigned s = (t < nb) ? bsum[t] : 0u;
    sd[t] = s;
    __syncthreads();
    for (int off = 1; off < 1024; off <<= 1) {
        unsigned xv = (t >= off) ? sd[t - off] : 0u;
        __syncthreads();
        sd[t] += xv;
        __syncthreads();
    }
    if (t < nb) bsum[t] = sd[t] - s;
}

__global__ __launch_bounds__(256) void scanC_kernel(unsigned* __restrict__ rowptr,
                                                    const unsigned* __restrict__ bsum,
                                                    int N, int E) {
    int base = blockIdx.x * 1024 + threadIdx.x * 4;
    unsigned off = bsum[blockIdx.x];
#pragma unroll
    for (int j = 0; j < 4; j++) {
        int i = base + j;
        if (i < N) rowptr[i] += off;
    }
    if (blockIdx.x == 0 && threadIdx.x == 0) rowptr[N] = (unsigned)E;
}

__global__ __launch_bounds__(1024) void bucket_fill(const uint2* __restrict__ part,
                                                    const unsigned* __restrict__ bc_base,
                                                    const unsigned* __restrict__ rowptr,
                                                    unsigned* __restrict__ col, int N) {
    __shared__ unsigned cur[NPB];
    int b = blockIdx.x;
    int node = (b << BSHIFT) + threadIdx.x;
    cur[threadIdx.x] = (node < N) ? rowptr[node] : 0u;
    __syncthreads();
    unsigned r0 = bc_base[b], r1 = bc_base[b + 1];
    for (unsigned i = r0 + threadIdx.x; i < r1; i += 1024) {
        uint2 e = part[i];
        unsigned p = atomicAdd(&cur[e.y & (NPB - 1)], 1u);
        col[p] = e.x;
    }
}

// ---------------- aggregation: z = (1+eps)*h + sum_{neigh} h ----------------
__global__ __launch_bounds__(128) void agg_kernel(
    const unsigned short* __restrict__ h, const unsigned* __restrict__ rowptr,
    const unsigned* __restrict__ col, const float* __restrict__ eps, int layer,
    unsigned short* __restrict__ z, int N) {
    int n = blockIdx.x * 2 + (threadIdx.x >> 6);
    if (n >= N) return;
    int lane = threadIdx.x & 63;
    int chunk = lane & 15;
    int sub = lane >> 4;
    unsigned r0 = rowptr[n], r1 = rowptr[n + 1];
    float acc0[8], acc1[8];
#pragma unroll
    for (int k = 0; k < 8; k++) { acc0[k] = 0.f; acc1[k] = 0.f; }
    unsigned j = r0 + sub;
    for (; j + 4 < r1; j += 8) {
        unsigned c0 = col[j], c1 = col[j + 4];
        bhalf8 v0 = *(const bhalf8*)&h[(size_t)c0 * H + chunk * 8];
        bhalf8 v1 = *(const bhalf8*)&h[(size_t)c1 * H + chunk * 8];
#pragma unroll
        for (int k = 0; k < 8; k++) {
            acc0[k] += bf2f((unsigned short)v0[k]);
            acc1[k] += bf2f((unsigned short)v1[k]);
        }
    }
    if (j < r1) {
        unsigned c0 = col[j];
        bhalf8 v0 = *(const bhalf8*)&h[(size_t)c0 * H + chunk * 8];
#pragma unroll
        for (int k = 0; k < 8; k++) acc0[k] += bf2f((unsigned short)v0[k]);
    }
#pragma unroll
    for (int k = 0; k < 8; k++) {
        acc0[k] += acc1[k];
        acc0[k] += __shfl_xor(acc0[k], 16, 64);
        acc0[k] += __shfl_xor(acc0[k], 32, 64);
    }
    if (sub == 0) {
        float e = 1.0f + eps[layer];
        bhalf8 hv = *(const bhalf8*)&h[(size_t)n * H + chunk * 8];
        bhalf8 o;
#pragma unroll
        for (int k = 0; k < 8; k++)
            o[k] = (short)f2bf(e * bf2f((unsigned short)hv[k]) + acc0[k]);
        *(bhalf8*)&z[(size_t)n * H + chunk * 8] = o;
    }
}

// ---------------- fused MLP: h = relu(bn2(relu(bn1(z@W1))@W2)) ----------------
// Block = 4 waves, 64 rows. Stage1: each wave computes t-quadrant [64 x 64],
// bn1+relu, deposit bf16 into padded LDS [64][LDP]. Stage2: A from LDS,
// B (W2T) from global (L2-resident), bn2+relu, write h.
#define LDP 264  // padded row stride (ushorts): 2-way bank aliasing only
__global__ __launch_bounds__(256) void mlp_fused_kernel(
    const unsigned short* __restrict__ z, const unsigned short* __restrict__ W1T,
    const unsigned short* __restrict__ W2T,
    const float* __restrict__ sc1, const float* __restrict__ sh1,
    const float* __restrict__ sc2, const float* __restrict__ sh2,
    unsigned short* __restrict__ h, int N) {
    __shared__ unsigned short tl[64 * LDP];
    int wave = threadIdx.x >> 6, lane = threadIdx.x & 63;
    int rtile = blockIdx.x * 64;
    int rlane = lane & 15;
    int kq = lane >> 4;
    int kg = kq * 8;
    int arow[4];
#pragma unroll
    for (int rb = 0; rb < 4; rb++) {
        int r = rtile + rb * 16 + rlane;
        arow[rb] = r < N ? r : N - 1;
    }
    f32x4 zero = {0.f, 0.f, 0.f, 0.f};
    // ---- stage 1: t = relu(bn1(z @ W1)), 64 rows x 64 cols per wave ----
    {
        int wcol = wave * 64;
        f32x4 acc[4][4];
#pragma unroll
        for (int rb = 0; rb < 4; rb++)
#pragma unroll
            for (int cb = 0; cb < 4; cb++) acc[rb][cb] = zero;
#pragma unroll
        for (int ks = 0; ks < 4; ks++) {
            bhalf8 a[4], b[4];
#pragma unroll
            for (int rb = 0; rb < 4; rb++)
                a[rb] = *(const bhalf8*)&z[(size_t)arow[rb] * H + ks * 32 + kg];
#pragma unroll
            for (int cb = 0; cb < 4; cb++)
                b[cb] = *(const bhalf8*)&W1T[(size_t)(wcol + cb * 16 + rlane) * H + ks * 32 + kg];
#pragma unroll
            for (int rb = 0; rb < 4; rb++)
#pragma unroll
                for (int cb = 0; cb < 4; cb++)
                    acc[rb][cb] = __builtin_amdgcn_mfma_f32_16x16x32_bf16(a[rb], b[cb], acc[rb][cb], 0, 0, 0);
        }
#pragma unroll
        for (int cb = 0; cb < 4; cb++) {
            int colc = wcol + cb * 16 + rlane;
            float sc = sc1[colc], sh = sh1[colc];
#pragma unroll
            for (int rb = 0; rb < 4; rb++) {
#pragma unroll
                for (int j = 0; j < 4; j++) {
                    int rl = rb * 16 + kq * 4 + j;
                    float vv = acc[rb][cb][j] * sc + sh;
                    vv = vv > 0.f ? vv : 0.f;
                    tl[rl * LDP + colc] = f2bf(vv);
                }
            }
        }
    }
    __syncthreads();
    // ---- stage 2: h = relu(bn2(t @ W2)), 64 rows x 32 cols per wave ----
    {
        int wcol = wave * 32;
        f32x4 acc[4][2];
#pragma unroll
        for (int rb = 0; rb < 4; rb++)
#pragma unroll
            for (int cb = 0; cb < 2; cb++) acc[rb][cb] = zero;
#pragma unroll
        for (int ks = 0; ks < 8; ks++) {
            bhalf8 a[4], b[2];
#pragma unroll
            for (int rb = 0; rb < 4; rb++)
                a[rb] = *(const bhalf8*)&tl[(rb * 16 + rlane) * LDP + ks * 32 + kg];
#pragma unroll
            for (int cb = 0; cb < 2; cb++)
                b[cb] = *(const bhalf8*)&W2T[(size_t)(wcol + cb * 16 + rlane) * H2 + ks * 32 + kg];
#pragma unroll
            for (int rb = 0; rb < 4; rb++)
#pragma unroll
                for (int cb = 0; cb < 2; cb++)
                    acc[rb][cb] = __builtin_amdgcn_mfma_f32_16x16x32_bf16(a[rb], b[cb], acc[rb][cb], 0, 0, 0);
        }
        int rr = rtile + kq * 4;
#pragma unroll
        for (int cb = 0; cb < 2; cb++) {
            int colc = wcol + cb * 16 + rlane;
            float sc = sc2[colc], sh = sh2[colc];
#pragma unroll
            for (int rb = 0; rb < 4; rb++) {
#pragma unroll
                for (int j = 0; j < 4; j++) {
                    int row = rr + rb * 16 + j;
                    if (row < N) {
                        float vv = acc[rb][cb][j] * sc + sh;
                        vv = vv > 0.f ? vv : 0.f;
                        h[(size_t)row * H + colc] = f2bf(vv);
                    }
                }
            }
        }
    }
}

// ---------------- global mean pool ----------------
__global__ __launch_bounds__(128) void pool_kernel(
    const unsigned short* __restrict__ h, const int* __restrict__ batch,
    float* __restrict__ out, int N, int G) {
    __shared__ int se[2];
    int g = blockIdx.x;
    if (threadIdx.x == 0) {
        int lo = 0, hi = N;
        while (lo < hi) {
            int mid = (lo + hi) >> 1;
            if (batch[mid] < g) lo = mid + 1; else hi = mid;
        }
        se[0] = lo;
        hi = N;
        while (lo < hi) {
            int mid = (lo + hi) >> 1;
            if (batch[mid] < g + 1) lo = mid + 1; else hi = mid;
        }
        se[1] = lo;
    }
    __syncthreads();
    int s = se[0], e = se[1];
    int f = threadIdx.x;
    float acc = 0.f;
    for (int r = s; r < e; ++r) acc += bf2f(h[(size_t)r * H + f]);
    int cnt = e - s;
    out[(size_t)g * H + f] = cnt > 0 ? acc / (float)cnt : 0.f;
}

// ---------------- launch ----------------
extern "C" void kernel_launch(void* const* d_in, const int* in_sizes, int n_in,
                              void* d_out, int out_size, void* d_ws, size_t ws_size,
                              hipStream_t stream) {
    const float* x     = (const float*)d_in[0];
    const int*   ei    = (const int*)d_in[1];
    const int*   batch = (const int*)d_in[2];
    const float* Wemb  = (const float*)d_in[3];
    const float* bemb  = (const float*)d_in[4];
    const float* eps   = (const float*)d_in[5];
    const float* W1    = (const float*)d_in[6];
    const float* b1    = (const float*)d_in[7];
    const float* g1    = (const float*)d_in[8];
    const float* be1   = (const float*)d_in[9];
    const float* m1    = (const float*)d_in[10];
    const float* v1    = (const float*)d_in[11];
    const float* W2    = (const float*)d_in[12];
    const float* b2    = (const float*)d_in[13];
    const float* g2    = (const float*)d_in[14];
    const float* be2   = (const float*)d_in[15];
    const float* m2    = (const float*)d_in[16];
    const float* v2    = (const float*)d_in[17];

    int N = in_sizes[0] / 9;
    int E = in_sizes[1] / 2;
    int G = out_size / H;
    int nbc = (N + NPB - 1) >> BSHIFT;

    char* p = (char*)d_ws;
    auto alloc = [&](size_t bytes) -> char* {
        char* r = p;
        p += (bytes + 255) & ~(size_t)255;
        return r;
    };
    unsigned short* h   = (unsigned short*)alloc((size_t)N * H * 2);
    unsigned short* z   = (unsigned short*)alloc((size_t)N * H * 2);
    uint2*          part = (uint2*)alloc((size_t)E * 8);
    unsigned*       rowptr = (unsigned*)alloc((size_t)(N + 1) * 4);
    unsigned*       gdeg   = (unsigned*)alloc((size_t)N * 4);
    unsigned*       bsum   = (unsigned*)alloc(1024 * 4);
    unsigned*       col    = (unsigned*)alloc((size_t)E * 4);
    unsigned short* W1T = (unsigned short*)alloc((size_t)NLAYERS * H * H2 * 2);
    unsigned short* W2T = (unsigned short*)alloc((size_t)NLAYERS * H * H2 * 2);
    float* sc1 = (float*)alloc(NLAYERS * H2 * 4);
    float* sh1 = (float*)alloc(NLAYERS * H2 * 4);
    float* sc2 = (float*)alloc(NLAYERS * H * 4);
    float* sh2 = (float*)alloc(NLAYERS * H * 4);
    unsigned* bc_cnt    = (unsigned*)alloc((NBC + 2) * 4);
    unsigned* bc_base   = (unsigned*)alloc((NBC + 2) * 4);
    unsigned* bc_cursor = (unsigned*)alloc((NBC + 2) * 4);

    hipMemsetAsync(bc_cnt, 0, (NBC + 2) * 4, stream);
    prep_params<<<1, 1024, 0, stream>>>(b1, g1, be1, m1, v1, b2, g2, be2, m2, v2,
                                        sc1, sh1, sc2, sh2);
    prep_weights<<<(NLAYERS * H * H2 + 255) / 256, 256, 0, stream>>>(W1, W2, W1T, W2T);
    embed_kernel<<<(N + 1) / 2, 256, 0, stream>>>(x, Wemb, bemb, h, N);

    // CSR build
    hist_coarse<<<512, 256, 0, stream>>>(ei, bc_cnt, E, nbc);
    scan_coarse<<<1, 128, 0, stream>>>(bc_cnt, bc_base, bc_cursor, nbc, E);
    partition_kernel<<<(E + PART_BATCH - 1) / PART_BATCH, 256, 0, stream>>>(
        ei, bc_cursor, part, E, nbc);
    bucket_degrees<<<nbc, 1024, 0, stream>>>(part, bc_base, gdeg, N);
    int nb = (N + 1023) / 1024;
    scanA_kernel<<<nb, 256, 0, stream>>>(gdeg, rowptr, bsum, N);
    scanB_kernel<<<1, 1024, 0, stream>>>(bsum, nb);
    scanC_kernel<<<nb, 256, 0, stream>>>(rowptr, bsum, N, E);
    bucket_fill<<<nbc, 1024, 0, stream>>>(part, bc_base, rowptr, col, N);

    for (int l = 0; l < NLAYERS; l++) {
        agg_kernel<<<(N + 1) / 2, 128, 0, stream>>>(h, rowptr, col, eps, l, z, N);
        mlp_fused_kernel<<<(N + 63) / 64, 256, 0, stream>>>(
            z, W1T + (size_t)l * H * H2, W2T + (size_t)l * H * H2,
            sc1 + l * H2, sh1 + l * H2, sc2 + l * H, sh2 + l * H, h, N);
    }
    pool_kernel<<<G, 128, 0, stream>>>(h, batch, (float*)d_out, N, G);
}

// Round 10
// 929.152 us; speedup vs baseline: 1.2635x; 1.0387x over previous
//
#include <hip/hip_runtime.h>
#include <stdint.h>

#define H 128
#define H2 256
#define NLAYERS 4
#define BN_EPS 1e-5f

// CSR bucketing
#define BSHIFT 10
#define NPB 1024
#define NBC 98
#define PART_BATCH 2048
#define EPT 8

typedef __attribute__((ext_vector_type(4))) float f32x4;
typedef __attribute__((ext_vector_type(8))) short bhalf8;

__device__ __forceinline__ float bf2f(unsigned short u) {
    union { unsigned int i; float f; } v;
    v.i = ((unsigned int)u) << 16;
    return v.f;
}
__device__ __forceinline__ unsigned short f2bf(float f) {
    union { float f; unsigned int i; } v;
    v.f = f;
    unsigned int b = v.i + 0x7FFFu + ((v.i >> 16) & 1u);
    return (unsigned short)(b >> 16);
}

// ---------------- embedding: h = x @ Wemb + bemb  (bf16 out) ----------------
__global__ __launch_bounds__(256) void embed_kernel(
    const float* __restrict__ x, const float* __restrict__ Wemb,
    const float* __restrict__ bemb, unsigned short* __restrict__ h, int N) {
    int n = blockIdx.x * 2 + (threadIdx.x >> 7);
    int f = threadIdx.x & 127;
    if (n >= N) return;
    const float* xr = x + (size_t)n * 9;
    float acc = bemb[f];
#pragma unroll
    for (int k = 0; k < 9; k++) acc += xr[k] * Wemb[k * H + f];
    h[(size_t)n * H + f] = f2bf(acc);
}

// ---------------- BN param fold ----------------
__global__ void prep_params(
    const float* __restrict__ b1, const float* __restrict__ g1, const float* __restrict__ be1,
    const float* __restrict__ m1, const float* __restrict__ v1,
    const float* __restrict__ b2, const float* __restrict__ g2, const float* __restrict__ be2,
    const float* __restrict__ m2, const float* __restrict__ v2,
    float* __restrict__ sc1, float* __restrict__ sh1,
    float* __restrict__ sc2, float* __restrict__ sh2) {
    int t = threadIdx.x;  // 1024 threads
    if (t < NLAYERS * H2) {
        float s = g1[t] * rsqrtf(v1[t] + BN_EPS);
        sc1[t] = s;
        sh1[t] = (b1[t] - m1[t]) * s + be1[t];
    }
    if (t < NLAYERS * H) {
        float s = g2[t] * rsqrtf(v2[t] + BN_EPS);
        sc2[t] = s;
        sh2[t] = (b2[t] - m2[t]) * s + be2[t];
    }
}

// ---------------- weight fragment-order pack + bf16 convert ----------------
// W1F: idx = ((((l*16 + c16)*4 + ks)*64 + lane)*8 + e)
//   c = c16*16 + (lane&15); k = ks*32 + (lane>>4)*8 + e;  value = W1[l][k][c]
// W2F: idx = ((((l*8 + c16)*8 + ks)*64 + lane)*8 + e)
//   c = c16*16 + (lane&15); k = ks*32 + (lane>>4)*8 + e;  value = W2[l][k][c]
// A wave-load of 64 lanes x 16B at (c16, ks) is 1KB contiguous.
__global__ __launch_bounds__(256) void prep_weights(
    const float* __restrict__ W1, const float* __restrict__ W2,
    unsigned short* __restrict__ W1F, unsigned short* __restrict__ W2F) {
    int idx = blockIdx.x * 256 + threadIdx.x;
    if (idx >= NLAYERS * H * H2) return;
    {
        int e = idx & 7;
        int lane = (idx >> 3) & 63;
        int ks = (idx >> 9) & 3;
        int c16 = (idx >> 11) & 15;
        int l = idx >> 15;
        int c = c16 * 16 + (lane & 15);
        int k = ks * 32 + (lane >> 4) * 8 + e;
        W1F[idx] = f2bf(W1[((size_t)l * H + k) * H2 + c]);
    }
    {
        int e = idx & 7;
        int lane = (idx >> 3) & 63;
        int ks = (idx >> 9) & 7;
        int c16 = (idx >> 12) & 7;
        int l = idx >> 15;
        int c = c16 * 16 + (lane & 15);
        int k = ks * 32 + (lane >> 4) * 8 + e;
        W2F[idx] = f2bf(W2[((size_t)l * H2 + k) * H + c]);
    }
}

// ---------------- CSR build (bucketed, write-locality-aware) ----------------
__global__ __launch_bounds__(256) void hist_coarse(const int* __restrict__ ei,
                                                   unsigned* __restrict__ bc_cnt,
                                                   int E, int nbc) {
    __shared__ unsigned lh[NBC];
    for (int i = threadIdx.x; i < nbc; i += 256) lh[i] = 0;
    __syncthreads();
    for (int e = blockIdx.x * 256 + threadIdx.x; e < E; e += gridDim.x * 256)
        atomicAdd(&lh[(unsigned)ei[E + e] >> BSHIFT], 1u);
    __syncthreads();
    for (int i = threadIdx.x; i < nbc; i += 256)
        if (lh[i]) atomicAdd(&bc_cnt[i], lh[i]);
}

__global__ __launch_bounds__(128) void scan_coarse(const unsigned* __restrict__ bc_cnt,
                                                   unsigned* __restrict__ bc_base,
                                                   unsigned* __restrict__ bc_cursor,
                                                   int nbc, int E) {
    __shared__ unsigned sd[128];
    int t = threadIdx.x;
    unsigned v = (t < nbc) ? bc_cnt[t] : 0u;
    sd[t] = v;
    __syncthreads();
    for (int off = 1; off < 128; off <<= 1) {
        unsigned xv = (t >= off) ? sd[t - off] : 0u;
        __syncthreads();
        sd[t] += xv;
        __syncthreads();
    }
    unsigned excl = sd[t] - v;
    if (t < nbc) {
        bc_base[t] = excl;
        bc_cursor[t] = excl;
    }
    if (t == 0) bc_base[nbc] = (unsigned)E;
}

__global__ __launch_bounds__(256) void partition_kernel(const int* __restrict__ ei,
                                                        unsigned* __restrict__ bc_cursor,
                                                        uint2* __restrict__ part,
                                                        int E, int nbc) {
    __shared__ unsigned lh[NBC];
    __shared__ unsigned lb[NBC];
    for (int i = threadIdx.x; i < nbc; i += 256) lh[i] = 0;
    __syncthreads();
    int base = blockIdx.x * PART_BATCH;
    int s[EPT], d[EPT];
    unsigned rank[EPT];
    int bk[EPT];
#pragma unroll
    for (int k = 0; k < EPT; k++) {
        int e = base + k * 256 + threadIdx.x;
        if (e < E) {
            s[k] = ei[e];
            d[k] = ei[E + e];
            bk[k] = (unsigned)d[k] >> BSHIFT;
            rank[k] = atomicAdd(&lh[bk[k]], 1u);
        } else bk[k] = -1;
    }
    __syncthreads();
    for (int i = threadIdx.x; i < nbc; i += 256)
        lb[i] = lh[i] ? atomicAdd(&bc_cursor[i], lh[i]) : 0u;
    __syncthreads();
#pragma unroll
    for (int k = 0; k < EPT; k++) {
        if (bk[k] >= 0) {
            unsigned p = lb[bk[k]] + rank[k];
            part[p] = make_uint2((unsigned)s[k], (unsigned)d[k]);
        }
    }
}

__global__ __launch_bounds__(1024) void bucket_degrees(const uint2* __restrict__ part,
                                                       const unsigned* __restrict__ bc_base,
                                                       unsigned* __restrict__ gdeg, int N) {
    __shared__ unsigned deg[NPB];
    int b = blockIdx.x;
    deg[threadIdx.x] = 0;
    __syncthreads();
    unsigned r0 = bc_base[b], r1 = bc_base[b + 1];
    for (unsigned i = r0 + threadIdx.x; i < r1; i += 1024)
        atomicAdd(&deg[part[i].y & (NPB - 1)], 1u);
    __syncthreads();
    int node = (b << BSHIFT) + threadIdx.x;
    if (node < N) gdeg[node] = deg[threadIdx.x];
}

__global__ __launch_bounds__(256) void scanA_kernel(const unsigned* __restrict__ deg,
                                                    unsigned* __restrict__ rowptr,
                                                    unsigned* __restrict__ bsum, int N) {
    __shared__ unsigned sd[256];
    int tid = threadIdx.x;
    int base = blockIdx.x * 1024 + tid * 4;
    unsigned v[4];
    unsigned s = 0;
#pragma unroll
    for (int j = 0; j < 4; j++) {
        v[j] = (base + j < N) ? deg[base + j] : 0u;
        s += v[j];
    }
    sd[tid] = s;
    __syncthreads();
    for (int off = 1; off < 256; off <<= 1) {
        unsigned xv = (tid >= off) ? sd[tid - off] : 0u;
        __syncthreads();
        sd[tid] += xv;
        __syncthreads();
    }
    unsigned excl = sd[tid] - s;
#pragma unroll
    for (int j = 0; j < 4; j++) {
        if (base + j < N) rowptr[base + j] = excl;
        excl += v[j];
    }
    if (tid == 255) bsum[blockIdx.x] = sd[255];
}

__global__ __launch_bounds__(1024) void scanB_kernel(unsigned* __restrict__ bsum, int nb) {
    __shared__ unsigned sd[1024];
    int t = threadIdx.x;
    unsigned s = (t < nb) ? bsum[t] : 0u;
    sd[t] = s;
    __syncthreads();
    for (int off = 1; off < 1024; off <<= 1) {
        unsigned xv = (t >= off) ? sd[t - off] : 0u;
        __syncthreads();
        sd[t] += xv;
        __syncthreads();
    }
    if (t < nb) bsum[t] = sd[t] - s;
}

__global__ __launch_bounds__(256) void scanC_kernel(unsigned* __restrict__ rowptr,
                                                    const unsigned* __restrict__ bsum,
                                                    int N, int E) {
    int base = blockIdx.x * 1024 + threadIdx.x * 4;
    unsigned off = bsum[blockIdx.x];
#pragma unroll
    for (int j = 0; j < 4; j++) {
        int i = base + j;
        if (i < N) rowptr[i] += off;
    }
    if (blockIdx.x == 0 && threadIdx.x == 0) rowptr[N] = (unsigned)E;
}

__global__ __launch_bounds__(1024) void bucket_fill(const uint2* __restrict__ part,
                                                    const unsigned* __restrict__ bc_base,
                                                    const unsigned* __restrict__ rowptr,
                                                    unsigned* __restrict__ col, int N) {
    __shared__ unsigned cur[NPB];
    int b = blockIdx.x;
    int node = (b << BSHIFT) + threadIdx.x;
    cur[threadIdx.x] = (node < N) ? rowptr[node] : 0u;
    __syncthreads();
    unsigned r0 = bc_base[b], r1 = bc_base[b + 1];
    for (unsigned i = r0 + threadIdx.x; i < r1; i += 1024) {
        uint2 e = part[i];
        unsigned p = atomicAdd(&cur[e.y & (NPB - 1)], 1u);
        col[p] = e.x;
    }
}

// ---------------- aggregation: z = (1+eps)*h + sum_{neigh} h ----------------
// 4 nodes per 256-thread block; 1 wave per node; 16 neighbor rows in flight
// (4 subs x 4 independent accumulator sets).
__global__ __launch_bounds__(256) void agg_kernel(
    const unsigned short* __restrict__ h, const unsigned* __restrict__ rowptr,
    const unsigned* __restrict__ col, const float* __restrict__ eps, int layer,
    unsigned short* __restrict__ z, int N) {
    int n = blockIdx.x * 4 + (threadIdx.x >> 6);
    if (n >= N) return;
    int lane = threadIdx.x & 63;
    int chunk = lane & 15;
    int sub = lane >> 4;
    unsigned r0 = rowptr[n], r1 = rowptr[n + 1];
    float a0[8], a1[8], a2[8], a3[8];
#pragma unroll
    for (int k = 0; k < 8; k++) { a0[k] = 0.f; a1[k] = 0.f; a2[k] = 0.f; a3[k] = 0.f; }
    unsigned j = r0 + sub;
    for (; j + 12 < r1; j += 16) {
        unsigned c0 = col[j], c1 = col[j + 4], c2 = col[j + 8], c3 = col[j + 12];
        bhalf8 v0 = *(const bhalf8*)&h[(size_t)c0 * H + chunk * 8];
        bhalf8 v1 = *(const bhalf8*)&h[(size_t)c1 * H + chunk * 8];
        bhalf8 v2 = *(const bhalf8*)&h[(size_t)c2 * H + chunk * 8];
        bhalf8 v3 = *(const bhalf8*)&h[(size_t)c3 * H + chunk * 8];
#pragma unroll
        for (int k = 0; k < 8; k++) {
            a0[k] += bf2f((unsigned short)v0[k]);
            a1[k] += bf2f((unsigned short)v1[k]);
            a2[k] += bf2f((unsigned short)v2[k]);
            a3[k] += bf2f((unsigned short)v3[k]);
        }
    }
    for (; j < r1; j += 4) {
        unsigned c0 = col[j];
        bhalf8 v0 = *(const bhalf8*)&h[(size_t)c0 * H + chunk * 8];
#pragma unroll
        for (int k = 0; k < 8; k++) a0[k] += bf2f((unsigned short)v0[k]);
    }
#pragma unroll
    for (int k = 0; k < 8; k++) {
        a0[k] += a1[k] + (a2[k] + a3[k]);
        a0[k] += __shfl_xor(a0[k], 16, 64);
        a0[k] += __shfl_xor(a0[k], 32, 64);
    }
    if (sub == 0) {
        float e = 1.0f + eps[layer];
        bhalf8 hv = *(const bhalf8*)&h[(size_t)n * H + chunk * 8];
        bhalf8 o;
#pragma unroll
        for (int k = 0; k < 8; k++)
            o[k] = (short)f2bf(e * bf2f((unsigned short)hv[k]) + a0[k]);
        *(bhalf8*)&z[(size_t)n * H + chunk * 8] = o;
    }
}

// ---------------- fused MLP: h = relu(bn2(relu(bn1(z@W1))@W2)) ----------------
// Block = 4 waves, 64 rows. B-operands in fragment order: coalesced 1KB loads.
#define LDP 264
__global__ __launch_bounds__(256) void mlp_fused_kernel(
    const unsigned short* __restrict__ z, const unsigned short* __restrict__ W1F,
    const unsigned short* __restrict__ W2F,
    const float* __restrict__ sc1, const float* __restrict__ sh1,
    const float* __restrict__ sc2, const float* __restrict__ sh2,
    unsigned short* __restrict__ h, int N) {
    __shared__ unsigned short tl[64 * LDP];
    int wave = threadIdx.x >> 6, lane = threadIdx.x & 63;
    int rtile = blockIdx.x * 64;
    int rlane = lane & 15;
    int kq = lane >> 4;
    int kg = kq * 8;
    int arow[4];
#pragma unroll
    for (int rb = 0; rb < 4; rb++) {
        int r = rtile + rb * 16 + rlane;
        arow[rb] = r < N ? r : N - 1;
    }
    f32x4 zero = {0.f, 0.f, 0.f, 0.f};
    // ---- stage 1: t = relu(bn1(z @ W1)), 64 rows x 64 cols per wave ----
    {
        f32x4 acc[4][4];
#pragma unroll
        for (int rb = 0; rb < 4; rb++)
#pragma unroll
            for (int cb = 0; cb < 4; cb++) acc[rb][cb] = zero;
#pragma unroll
        for (int ks = 0; ks < 4; ks++) {
            bhalf8 a[4], b[4];
#pragma unroll
            for (int rb = 0; rb < 4; rb++)
                a[rb] = *(const bhalf8*)&z[(size_t)arow[rb] * H + ks * 32 + kg];
#pragma unroll
            for (int cb = 0; cb < 4; cb++)
                b[cb] = *(const bhalf8*)&W1F[((size_t)((wave * 4 + cb) * 4 + ks) * 64 + lane) * 8];
#pragma unroll
            for (int rb = 0; rb < 4; rb++)
#pragma unroll
                for (int cb = 0; cb < 4; cb++)
                    acc[rb][cb] = __builtin_amdgcn_mfma_f32_16x16x32_bf16(a[rb], b[cb], acc[rb][cb], 0, 0, 0);
        }
#pragma unroll
        for (int cb = 0; cb < 4; cb++) {
            int colc = wave * 64 + cb * 16 + rlane;
            float sc = sc1[colc], sh = sh1[colc];
#pragma unroll
            for (int rb = 0; rb < 4; rb++) {
#pragma unroll
                for (int j = 0; j < 4; j++) {
                    int rl = rb * 16 + kq * 4 + j;
                    float vv = acc[rb][cb][j] * sc + sh;
                    vv = vv > 0.f ? vv : 0.f;
                    tl[rl * LDP + colc] = f2bf(vv);
                }
            }
        }
    }
    __syncthreads();
    // ---- stage 2: h = relu(bn2(t @ W2)), 64 rows x 32 cols per wave ----
    {
        f32x4 acc[4][2];
#pragma unroll
        for (int rb = 0; rb < 4; rb++)
#pragma unroll
            for (int cb = 0; cb < 2; cb++) acc[rb][cb] = zero;
#pragma unroll
        for (int ks = 0; ks < 8; ks++) {
            bhalf8 a[4], b[2];
#pragma unroll
            for (int rb = 0; rb < 4; rb++)
                a[rb] = *(const bhalf8*)&tl[(rb * 16 + rlane) * LDP + ks * 32 + kg];
#pragma unroll
            for (int cb = 0; cb < 2; cb++)
                b[cb] = *(const bhalf8*)&W2F[((size_t)((wave * 2 + cb) * 8 + ks) * 64 + lane) * 8];
#pragma unroll
            for (int rb = 0; rb < 4; rb++)
#pragma unroll
                for (int cb = 0; cb < 2; cb++)
                    acc[rb][cb] = __builtin_amdgcn_mfma_f32_16x16x32_bf16(a[rb], b[cb], acc[rb][cb], 0, 0, 0);
        }
        int rr = rtile + kq * 4;
#pragma unroll
        for (int cb = 0; cb < 2; cb++) {
            int colc = wave * 32 + cb * 16 + rlane;
            float sc = sc2[colc], sh = sh2[colc];
#pragma unroll
            for (int rb = 0; rb < 4; rb++) {
#pragma unroll
                for (int j = 0; j < 4; j++) {
                    int row = rr + rb * 16 + j;
                    if (row < N) {
                        float vv = acc[rb][cb][j] * sc + sh;
                        vv = vv > 0.f ? vv : 0.f;
                        h[(size_t)row * H + colc] = f2bf(vv);
                    }
                }
            }
        }
    }
}

// ---------------- global mean pool ----------------
__global__ __launch_bounds__(128) void pool_kernel(
    const unsigned short* __restrict__ h, const int* __restrict__ batch,
    float* __restrict__ out, int N, int G) {
    __shared__ int se[2];
    int g = blockIdx.x;
    if (threadIdx.x == 0) {
        int lo = 0, hi = N;
        while (lo < hi) {
            int mid = (lo + hi) >> 1;
            if (batch[mid] < g) lo = mid + 1; else hi = mid;
        }
        se[0] = lo;
        hi = N;
        while (lo < hi) {
            int mid = (lo + hi) >> 1;
            if (batch[mid] < g + 1) lo = mid + 1; else hi = mid;
        }
        se[1] = lo;
    }
    __syncthreads();
    int s = se[0], e = se[1];
    int f = threadIdx.x;
    float acc = 0.f;
    for (int r = s; r < e; ++r) acc += bf2f(h[(size_t)r * H + f]);
    int cnt = e - s;
    out[(size_t)g * H + f] = cnt > 0 ? acc / (float)cnt : 0.f;
}

// ---------------- launch ----------------
extern "C" void kernel_launch(void* const* d_in, const int* in_sizes, int n_in,
                              void* d_out, int out_size, void* d_ws, size_t ws_size,
                              hipStream_t stream) {
    const float* x     = (const float*)d_in[0];
    const int*   ei    = (const int*)d_in[1];
    const int*   batch = (const int*)d_in[2];
    const float* Wemb  = (const float*)d_in[3];
    const float* bemb  = (const float*)d_in[4];
    const float* eps   = (const float*)d_in[5];
    const float* W1    = (const float*)d_in[6];
    const float* b1    = (const float*)d_in[7];
    const float* g1    = (const float*)d_in[8];
    const float* be1   = (const float*)d_in[9];
    const float* m1    = (const float*)d_in[10];
    const float* v1    = (const float*)d_in[11];
    const float* W2    = (const float*)d_in[12];
    const float* b2    = (const float*)d_in[13];
    const float* g2    = (const float*)d_in[14];
    const float* be2   = (const float*)d_in[15];
    const float* m2    = (const float*)d_in[16];
    const float* v2    = (const float*)d_in[17];

    int N = in_sizes[0] / 9;
    int E = in_sizes[1] / 2;
    int G = out_size / H;
    int nbc = (N + NPB - 1) >> BSHIFT;

    char* p = (char*)d_ws;
    auto alloc = [&](size_t bytes) -> char* {
        char* r = p;
        p += (bytes + 255) & ~(size_t)255;
        return r;
    };
    unsigned short* h   = (unsigned short*)alloc((size_t)N * H * 2);
    unsigned short* z   = (unsigned short*)alloc((size_t)N * H * 2);
    uint2*          part = (uint2*)alloc((size_t)E * 8);
    unsigned*       rowptr = (unsigned*)alloc((size_t)(N + 1) * 4);
    unsigned*       gdeg   = (unsigned*)alloc((size_t)N * 4);
    unsigned*       bsum   = (unsigned*)alloc(1024 * 4);
    unsigned*       col    = (unsigned*)alloc((size_t)E * 4);
    unsigned short* W1F = (unsigned short*)alloc((size_t)NLAYERS * H * H2 * 2);
    unsigned short* W2F = (unsigned short*)alloc((size_t)NLAYERS * H * H2 * 2);
    float* sc1 = (float*)alloc(NLAYERS * H2 * 4);
    float* sh1 = (float*)alloc(NLAYERS * H2 * 4);
    float* sc2 = (float*)alloc(NLAYERS * H * 4);
    float* sh2 = (float*)alloc(NLAYERS * H * 4);
    unsigned* bc_cnt    = (unsigned*)alloc((NBC + 2) * 4);
    unsigned* bc_base   = (unsigned*)alloc((NBC + 2) * 4);
    unsigned* bc_cursor = (unsigned*)alloc((NBC + 2) * 4);

    hipMemsetAsync(bc_cnt, 0, (NBC + 2) * 4, stream);
    prep_params<<<1, 1024, 0, stream>>>(b1, g1, be1, m1, v1, b2, g2, be2, m2, v2,
                                        sc1, sh1, sc2, sh2);
    prep_weights<<<(NLAYERS * H * H2 + 255) / 256, 256, 0, stream>>>(W1, W2, W1F, W2F);
    embed_kernel<<<(N + 1) / 2, 256, 0, stream>>>(x, Wemb, bemb, h, N);

    // CSR build
    hist_coarse<<<512, 256, 0, stream>>>(ei, bc_cnt, E, nbc);
    scan_coarse<<<1, 128, 0, stream>>>(bc_cnt, bc_base, bc_cursor, nbc, E);
    partition_kernel<<<(E + PART_BATCH - 1) / PART_BATCH, 256, 0, stream>>>(
        ei, bc_cursor, part, E, nbc);
    bucket_degrees<<<nbc, 1024, 0, stream>>>(part, bc_base, gdeg, N);
    int nb = (N + 1023) / 1024;
    scanA_kernel<<<nb, 256, 0, stream>>>(gdeg, rowptr, bsum, N);
    scanB_kernel<<<1, 1024, 0, stream>>>(bsum, nb);
    scanC_kernel<<<nb, 256, 0, stream>>>(rowptr, bsum, N, E);
    bucket_fill<<<nbc, 1024, 0, stream>>>(part, bc_base, rowptr, col, N);

    for (int l = 0; l < NLAYERS; l++) {
        agg_kernel<<<(N + 3) / 4, 256, 0, stream>>>(h, rowptr, col, eps, l, z, N);
        mlp_fused_kernel<<<(N + 63) / 64, 256, 0, stream>>>(
            z, W1F + (size_t)l * H * H2, W2F + (size_t)l * H * H2,
            sc1 + l * H2, sh1 + l * H2, sc2 + l * H, sh2 + l * H, h, N);
    }
    pool_kernel<<<G, 128, 0, stream>>>(h, batch, (float*)d_out, N, G);
}

// Round 11
// 853.064 us; speedup vs baseline: 1.3762x; 1.0892x over previous
//
#include <hip/hip_runtime.h>
#include <stdint.h>

#define H 128
#define H2 256
#define NLAYERS 4
#define BN_EPS 1e-5f

// CSR bucketing
#define BSHIFT 10
#define NPB 1024
#define NBC 98
#define PART_BATCH 2048
#define EPT 8

typedef __attribute__((ext_vector_type(4))) float f32x4;
typedef __attribute__((ext_vector_type(8))) short bhalf8;

__device__ __forceinline__ float bf2f(unsigned short u) {
    union { unsigned int i; float f; } v;
    v.i = ((unsigned int)u) << 16;
    return v.f;
}
__device__ __forceinline__ unsigned short f2bf(float f) {
    union { float f; unsigned int i; } v;
    v.f = f;
    unsigned int b = v.i + 0x7FFFu + ((v.i >> 16) & 1u);
    return (unsigned short)(b >> 16);
}

// ---------------- embedding: h = x @ Wemb + bemb  (bf16 out) ----------------
__global__ __launch_bounds__(256) void embed_kernel(
    const float* __restrict__ x, const float* __restrict__ Wemb,
    const float* __restrict__ bemb, unsigned short* __restrict__ h, int N) {
    int n = blockIdx.x * 2 + (threadIdx.x >> 7);
    int f = threadIdx.x & 127;
    if (n >= N) return;
    const float* xr = x + (size_t)n * 9;
    float acc = bemb[f];
#pragma unroll
    for (int k = 0; k < 9; k++) acc += xr[k] * Wemb[k * H + f];
    h[(size_t)n * H + f] = f2bf(acc);
}

// ---------------- BN param fold ----------------
__global__ void prep_params(
    const float* __restrict__ b1, const float* __restrict__ g1, const float* __restrict__ be1,
    const float* __restrict__ m1, const float* __restrict__ v1,
    const float* __restrict__ b2, const float* __restrict__ g2, const float* __restrict__ be2,
    const float* __restrict__ m2, const float* __restrict__ v2,
    float* __restrict__ sc1, float* __restrict__ sh1,
    float* __restrict__ sc2, float* __restrict__ sh2) {
    int t = threadIdx.x;  // 1024 threads
    if (t < NLAYERS * H2) {
        float s = g1[t] * rsqrtf(v1[t] + BN_EPS);
        sc1[t] = s;
        sh1[t] = (b1[t] - m1[t]) * s + be1[t];
    }
    if (t < NLAYERS * H) {
        float s = g2[t] * rsqrtf(v2[t] + BN_EPS);
        sc2[t] = s;
        sh2[t] = (b2[t] - m2[t]) * s + be2[t];
    }
}

// ---------------- weight fragment-order pack + bf16 convert ----------------
// W1F: idx = ((((l*16 + c16)*4 + ks)*64 + lane)*8 + e)
// W2F: idx = ((((l*8 + c16)*8 + ks)*64 + lane)*8 + e)
// c = c16*16 + (lane&15); k = ks*32 + (lane>>4)*8 + e
__global__ __launch_bounds__(256) void prep_weights(
    const float* __restrict__ W1, const float* __restrict__ W2,
    unsigned short* __restrict__ W1F, unsigned short* __restrict__ W2F) {
    int idx = blockIdx.x * 256 + threadIdx.x;
    if (idx >= NLAYERS * H * H2) return;
    {
        int e = idx & 7;
        int lane = (idx >> 3) & 63;
        int ks = (idx >> 9) & 3;
        int c16 = (idx >> 11) & 15;
        int l = idx >> 15;
        int c = c16 * 16 + (lane & 15);
        int k = ks * 32 + (lane >> 4) * 8 + e;
        W1F[idx] = f2bf(W1[((size_t)l * H + k) * H2 + c]);
    }
    {
        int e = idx & 7;
        int lane = (idx >> 3) & 63;
        int ks = (idx >> 9) & 7;
        int c16 = (idx >> 12) & 7;
        int l = idx >> 15;
        int c = c16 * 16 + (lane & 15);
        int k = ks * 32 + (lane >> 4) * 8 + e;
        W2F[idx] = f2bf(W2[((size_t)l * H2 + k) * H + c]);
    }
}

// ---------------- CSR build (bucketed; part packed: src<<10 | dst_local) ----
__global__ __launch_bounds__(256) void hist_coarse(const int* __restrict__ ei,
                                                   unsigned* __restrict__ bc_cnt,
                                                   int E, int nbc) {
    __shared__ unsigned lh[NBC];
    for (int i = threadIdx.x; i < nbc; i += 256) lh[i] = 0;
    __syncthreads();
    for (int e = blockIdx.x * 256 + threadIdx.x; e < E; e += gridDim.x * 256)
        atomicAdd(&lh[(unsigned)ei[E + e] >> BSHIFT], 1u);
    __syncthreads();
    for (int i = threadIdx.x; i < nbc; i += 256)
        if (lh[i]) atomicAdd(&bc_cnt[i], lh[i]);
}

__global__ __launch_bounds__(128) void scan_coarse(const unsigned* __restrict__ bc_cnt,
                                                   unsigned* __restrict__ bc_base,
                                                   unsigned* __restrict__ bc_cursor,
                                                   int nbc, int E) {
    __shared__ unsigned sd[128];
    int t = threadIdx.x;
    unsigned v = (t < nbc) ? bc_cnt[t] : 0u;
    sd[t] = v;
    __syncthreads();
    for (int off = 1; off < 128; off <<= 1) {
        unsigned xv = (t >= off) ? sd[t - off] : 0u;
        __syncthreads();
        sd[t] += xv;
        __syncthreads();
    }
    unsigned excl = sd[t] - v;
    if (t < nbc) {
        bc_base[t] = excl;
        bc_cursor[t] = excl;
    }
    if (t == 0) bc_base[nbc] = (unsigned)E;
}

__global__ __launch_bounds__(256) void partition_kernel(const int* __restrict__ ei,
                                                        unsigned* __restrict__ bc_cursor,
                                                        unsigned* __restrict__ part,
                                                        int E, int nbc) {
    __shared__ unsigned lh[NBC];
    __shared__ unsigned lb[NBC];
    for (int i = threadIdx.x; i < nbc; i += 256) lh[i] = 0;
    __syncthreads();
    int base = blockIdx.x * PART_BATCH;
    int s[EPT], d[EPT];
    unsigned rank[EPT];
    int bk[EPT];
#pragma unroll
    for (int k = 0; k < EPT; k++) {
        int e = base + k * 256 + threadIdx.x;
        if (e < E) {
            s[k] = ei[e];
            d[k] = ei[E + e];
            bk[k] = (unsigned)d[k] >> BSHIFT;
            rank[k] = atomicAdd(&lh[bk[k]], 1u);
        } else bk[k] = -1;
    }
    __syncthreads();
    for (int i = threadIdx.x; i < nbc; i += 256)
        lb[i] = lh[i] ? atomicAdd(&bc_cursor[i], lh[i]) : 0u;
    __syncthreads();
#pragma unroll
    for (int k = 0; k < EPT; k++) {
        if (bk[k] >= 0) {
            unsigned p = lb[bk[k]] + rank[k];
            part[p] = ((unsigned)s[k] << BSHIFT) | ((unsigned)d[k] & (NPB - 1));
        }
    }
}

__global__ __launch_bounds__(1024) void bucket_degrees(const unsigned* __restrict__ part,
                                                       const unsigned* __restrict__ bc_base,
                                                       unsigned* __restrict__ gdeg, int N) {
    __shared__ unsigned deg[NPB];
    int b = blockIdx.x;
    deg[threadIdx.x] = 0;
    __syncthreads();
    unsigned r0 = bc_base[b], r1 = bc_base[b + 1];
    for (unsigned i = r0 + threadIdx.x; i < r1; i += 1024)
        atomicAdd(&deg[part[i] & (NPB - 1)], 1u);
    __syncthreads();
    int node = (b << BSHIFT) + threadIdx.x;
    if (node < N) gdeg[node] = deg[threadIdx.x];
}

__global__ __launch_bounds__(256) void scanA_kernel(const unsigned* __restrict__ deg,
                                                    unsigned* __restrict__ rowptr,
                                                    unsigned* __restrict__ bsum, int N) {
    __shared__ unsigned sd[256];
    int tid = threadIdx.x;
    int base = blockIdx.x * 1024 + tid * 4;
    unsigned v[4];
    unsigned s = 0;
#pragma unroll
    for (int j = 0; j < 4; j++) {
        v[j] = (base + j < N) ? deg[base + j] : 0u;
        s += v[j];
    }
    sd[tid] = s;
    __syncthreads();
    for (int off = 1; off < 256; off <<= 1) {
        unsigned xv = (tid >= off) ? sd[tid - off] : 0u;
        __syncthreads();
        sd[tid] += xv;
        __syncthreads();
    }
    unsigned excl = sd[tid] - s;
#pragma unroll
    for (int j = 0; j < 4; j++) {
        if (base + j < N) rowptr[base + j] = excl;
        excl += v[j];
    }
    if (tid == 255) bsum[blockIdx.x] = sd[255];
}

__global__ __launch_bounds__(1024) void scanB_kernel(unsigned* __restrict__ bsum, int nb) {
    __shared__ unsigned sd[1024];
    int t = threadIdx.x;
    unsigned s = (t < nb) ? bsum[t] : 0u;
    sd[t] = s;
    __syncthreads();
    for (int off = 1; off < 1024; off <<= 1) {
        unsigned xv = (t >= off) ? sd[t - off] : 0u;
        __syncthreads();
        sd[t] += xv;
        __syncthreads();
    }
    if (t < nb) bsum[t] = sd[t] - s;
}

__global__ __launch_bounds__(256) void scanC_kernel(unsigned* __restrict__ rowptr,
                                                    const unsigned* __restrict__ bsum,
                                                    int N, int E) {
    int base = blockIdx.x * 1024 + threadIdx.x * 4;
    unsigned off = bsum[blockIdx.x];
#pragma unroll
    for (int j = 0; j < 4; j++) {
        int i = base + j;
        if (i < N) rowptr[i] += off;
    }
    if (blockIdx.x == 0 && threadIdx.x == 0) rowptr[N] = (unsigned)E;
}

__global__ __launch_bounds__(1024) void bucket_fill(const unsigned* __restrict__ part,
                                                    const unsigned* __restrict__ bc_base,
                                                    const unsigned* __restrict__ rowptr,
                                                    unsigned* __restrict__ col, int N) {
    __shared__ unsigned cur[NPB];
    int b = blockIdx.x;
    int node = (b << BSHIFT) + threadIdx.x;
    cur[threadIdx.x] = (node < N) ? rowptr[node] : 0u;
    __syncthreads();
    unsigned r0 = bc_base[b], r1 = bc_base[b + 1];
    for (unsigned i = r0 + threadIdx.x; i < r1; i += 1024) {
        unsigned e = part[i];
        unsigned p = atomicAdd(&cur[e & (NPB - 1)], 1u);
        col[p] = e >> BSHIFT;
    }
}

// ---------------- aggregation: z = (1+eps)*h + sum_{neigh} h ----------------
// Round-9 config: 2 nodes per 128-thread block; 8 neighbor rows in flight.
__global__ __launch_bounds__(128) void agg_kernel(
    const unsigned short* __restrict__ h, const unsigned* __restrict__ rowptr,
    const unsigned* __restrict__ col, const float* __restrict__ eps, int layer,
    unsigned short* __restrict__ z, int N) {
    int n = blockIdx.x * 2 + (threadIdx.x >> 6);
    if (n >= N) return;
    int lane = threadIdx.x & 63;
    int chunk = lane & 15;
    int sub = lane >> 4;
    unsigned r0 = rowptr[n], r1 = rowptr[n + 1];
    float acc0[8], acc1[8];
#pragma unroll
    for (int k = 0; k < 8; k++) { acc0[k] = 0.f; acc1[k] = 0.f; }
    unsigned j = r0 + sub;
    for (; j + 4 < r1; j += 8) {
        unsigned c0 = col[j], c1 = col[j + 4];
        bhalf8 v0 = *(const bhalf8*)&h[(size_t)c0 * H + chunk * 8];
        bhalf8 v1 = *(const bhalf8*)&h[(size_t)c1 * H + chunk * 8];
#pragma unroll
        for (int k = 0; k < 8; k++) {
            acc0[k] += bf2f((unsigned short)v0[k]);
            acc1[k] += bf2f((unsigned short)v1[k]);
        }
    }
    if (j < r1) {
        unsigned c0 = col[j];
        bhalf8 v0 = *(const bhalf8*)&h[(size_t)c0 * H + chunk * 8];
#pragma unroll
        for (int k = 0; k < 8; k++) acc0[k] += bf2f((unsigned short)v0[k]);
    }
#pragma unroll
    for (int k = 0; k < 8; k++) {
        acc0[k] += acc1[k];
        acc0[k] += __shfl_xor(acc0[k], 16, 64);
        acc0[k] += __shfl_xor(acc0[k], 32, 64);
    }
    if (sub == 0) {
        float e = 1.0f + eps[layer];
        bhalf8 hv = *(const bhalf8*)&h[(size_t)n * H + chunk * 8];
        bhalf8 o;
#pragma unroll
        for (int k = 0; k < 8; k++)
            o[k] = (short)f2bf(e * bf2f((unsigned short)hv[k]) + acc0[k]);
        *(bhalf8*)&z[(size_t)n * H + chunk * 8] = o;
    }
}

// ---------------- fused MLP: h = relu(bn2(relu(bn1(z@W1))@W2)) ----------------
#define LDP 264
__global__ __launch_bounds__(256) void mlp_fused_kernel(
    const unsigned short* __restrict__ z, const unsigned short* __restrict__ W1F,
    const unsigned short* __restrict__ W2F,
    const float* __restrict__ sc1, const float* __restrict__ sh1,
    const float* __restrict__ sc2, const float* __restrict__ sh2,
    unsigned short* __restrict__ h, int N) {
    __shared__ unsigned short tl[64 * LDP];
    int wave = threadIdx.x >> 6, lane = threadIdx.x & 63;
    int rtile = blockIdx.x * 64;
    int rlane = lane & 15;
    int kq = lane >> 4;
    int kg = kq * 8;
    int arow[4];
#pragma unroll
    for (int rb = 0; rb < 4; rb++) {
        int r = rtile + rb * 16 + rlane;
        arow[rb] = r < N ? r : N - 1;
    }
    f32x4 zero = {0.f, 0.f, 0.f, 0.f};
    // ---- stage 1 ----
    {
        f32x4 acc[4][4];
#pragma unroll
        for (int rb = 0; rb < 4; rb++)
#pragma unroll
            for (int cb = 0; cb < 4; cb++) acc[rb][cb] = zero;
#pragma unroll
        for (int ks = 0; ks < 4; ks++) {
            bhalf8 a[4], b[4];
#pragma unroll
            for (int rb = 0; rb < 4; rb++)
                a[rb] = *(const bhalf8*)&z[(size_t)arow[rb] * H + ks * 32 + kg];
#pragma unroll
            for (int cb = 0; cb < 4; cb++)
                b[cb] = *(const bhalf8*)&W1F[((size_t)((wave * 4 + cb) * 4 + ks) * 64 + lane) * 8];
#pragma unroll
            for (int rb = 0; rb < 4; rb++)
#pragma unroll
                for (int cb = 0; cb < 4; cb++)
                    acc[rb][cb] = __builtin_amdgcn_mfma_f32_16x16x32_bf16(a[rb], b[cb], acc[rb][cb], 0, 0, 0);
        }
#pragma unroll
        for (int cb = 0; cb < 4; cb++) {
            int colc = wave * 64 + cb * 16 + rlane;
            float sc = sc1[colc], sh = sh1[colc];
#pragma unroll
            for (int rb = 0; rb < 4; rb++) {
#pragma unroll
                for (int j = 0; j < 4; j++) {
                    int rl = rb * 16 + kq * 4 + j;
                    float vv = acc[rb][cb][j] * sc + sh;
                    vv = vv > 0.f ? vv : 0.f;
                    tl[rl * LDP + colc] = f2bf(vv);
                }
            }
        }
    }
    __syncthreads();
    // ---- stage 2 ----
    {
        f32x4 acc[4][2];
#pragma unroll
        for (int rb = 0; rb < 4; rb++)
#pragma unroll
            for (int cb = 0; cb < 2; cb++) acc[rb][cb] = zero;
#pragma unroll
        for (int ks = 0; ks < 8; ks++) {
            bhalf8 a[4], b[2];
#pragma unroll
            for (int rb = 0; rb < 4; rb++)
                a[rb] = *(const bhalf8*)&tl[(rb * 16 + rlane) * LDP + ks * 32 + kg];
#pragma unroll
            for (int cb = 0; cb < 2; cb++)
                b[cb] = *(const bhalf8*)&W2F[((size_t)((wave * 2 + cb) * 8 + ks) * 64 + lane) * 8];
#pragma unroll
            for (int rb = 0; rb < 4; rb++)
#pragma unroll
                for (int cb = 0; cb < 2; cb++)
                    acc[rb][cb] = __builtin_amdgcn_mfma_f32_16x16x32_bf16(a[rb], b[cb], acc[rb][cb], 0, 0, 0);
        }
        int rr = rtile + kq * 4;
#pragma unroll
        for (int cb = 0; cb < 2; cb++) {
            int colc = wave * 32 + cb * 16 + rlane;
            float sc = sc2[colc], sh = sh2[colc];
#pragma unroll
            for (int rb = 0; rb < 4; rb++) {
#pragma unroll
                for (int j = 0; j < 4; j++) {
                    int row = rr + rb * 16 + j;
                    if (row < N) {
                        float vv = acc[rb][cb][j] * sc + sh;
                        vv = vv > 0.f ? vv : 0.f;
                        h[(size_t)row * H + colc] = f2bf(vv);
                    }
                }
            }
        }
    }
}

// ---------------- global mean pool (8 rows in flight per graph) ----------------
__global__ __launch_bounds__(256) void pool_kernel(
    const unsigned short* __restrict__ h, const int* __restrict__ batch,
    float* __restrict__ out, int N, int G) {
    __shared__ float sacc[2][128];
    __shared__ int se[2];
    int g = blockIdx.x;
    if (threadIdx.x == 0) {
        int lo = 0, hi = N;
        while (lo < hi) {
            int mid = (lo + hi) >> 1;
            if (batch[mid] < g) lo = mid + 1; else hi = mid;
        }
        se[0] = lo;
        hi = N;
        while (lo < hi) {
            int mid = (lo + hi) >> 1;
            if (batch[mid] < g + 1) lo = mid + 1; else hi = mid;
        }
        se[1] = lo;
    }
    __syncthreads();
    int s = se[0], e = se[1];
    int f = threadIdx.x & 127;
    int half = threadIdx.x >> 7;
    float a0 = 0.f, a1 = 0.f, a2 = 0.f, a3 = 0.f;
    int r = s + half;
    for (; r + 6 < e; r += 8) {
        a0 += bf2f(h[(size_t)r * H + f]);
        a1 += bf2f(h[(size_t)(r + 2) * H + f]);
        a2 += bf2f(h[(size_t)(r + 4) * H + f]);
        a3 += bf2f(h[(size_t)(r + 6) * H + f]);
    }
    for (; r < e; r += 2) a0 += bf2f(h[(size_t)r * H + f]);
    sacc[half][f] = (a0 + a1) + (a2 + a3);
    __syncthreads();
    if (half == 0) {
        int cnt = e - s;
        float v = sacc[0][f] + sacc[1][f];
        out[(size_t)g * H + f] = cnt > 0 ? v / (float)cnt : 0.f;
    }
}

// ---------------- launch ----------------
extern "C" void kernel_launch(void* const* d_in, const int* in_sizes, int n_in,
                              void* d_out, int out_size, void* d_ws, size_t ws_size,
                              hipStream_t stream) {
    const float* x     = (const float*)d_in[0];
    const int*   ei    = (const int*)d_in[1];
    const int*   batch = (const int*)d_in[2];
    const float* Wemb  = (const float*)d_in[3];
    const float* bemb  = (const float*)d_in[4];
    const float* eps   = (const float*)d_in[5];
    const float* W1    = (const float*)d_in[6];
    const float* b1    = (const float*)d_in[7];
    const float* g1    = (const float*)d_in[8];
    const float* be1   = (const float*)d_in[9];
    const float* m1    = (const float*)d_in[10];
    const float* v1    = (const float*)d_in[11];
    const float* W2    = (const float*)d_in[12];
    const float* b2    = (const float*)d_in[13];
    const float* g2    = (const float*)d_in[14];
    const float* be2   = (const float*)d_in[15];
    const float* m2    = (const float*)d_in[16];
    const float* v2    = (const float*)d_in[17];

    int N = in_sizes[0] / 9;
    int E = in_sizes[1] / 2;
    int G = out_size / H;
    int nbc = (N + NPB - 1) >> BSHIFT;

    char* p = (char*)d_ws;
    auto alloc = [&](size_t bytes) -> char* {
        char* r = p;
        p += (bytes + 255) & ~(size_t)255;
        return r;
    };
    unsigned short* h   = (unsigned short*)alloc((size_t)N * H * 2);
    unsigned short* z   = (unsigned short*)alloc((size_t)N * H * 2);
    unsigned*       part = (unsigned*)alloc((size_t)E * 4);
    unsigned*       rowptr = (unsigned*)alloc((size_t)(N + 1) * 4);
    unsigned*       gdeg   = (unsigned*)alloc((size_t)N * 4);
    unsigned*       bsum   = (unsigned*)alloc(1024 * 4);
    unsigned*       col    = (unsigned*)alloc((size_t)E * 4);
    unsigned short* W1F = (unsigned short*)alloc((size_t)NLAYERS * H * H2 * 2);
    unsigned short* W2F = (unsigned short*)alloc((size_t)NLAYERS * H * H2 * 2);
    float* sc1 = (float*)alloc(NLAYERS * H2 * 4);
    float* sh1 = (float*)alloc(NLAYERS * H2 * 4);
    float* sc2 = (float*)alloc(NLAYERS * H * 4);
    float* sh2 = (float*)alloc(NLAYERS * H * 4);
    unsigned* bc_cnt    = (unsigned*)alloc((NBC + 2) * 4);
    unsigned* bc_base   = (unsigned*)alloc((NBC + 2) * 4);
    unsigned* bc_cursor = (unsigned*)alloc((NBC + 2) * 4);

    hipMemsetAsync(bc_cnt, 0, (NBC + 2) * 4, stream);
    prep_params<<<1, 1024, 0, stream>>>(b1, g1, be1, m1, v1, b2, g2, be2, m2, v2,
                                        sc1, sh1, sc2, sh2);
    prep_weights<<<(NLAYERS * H * H2 + 255) / 256, 256, 0, stream>>>(W1, W2, W1F, W2F);
    embed_kernel<<<(N + 1) / 2, 256, 0, stream>>>(x, Wemb, bemb, h, N);

    // CSR build
    hist_coarse<<<512, 256, 0, stream>>>(ei, bc_cnt, E, nbc);
    scan_coarse<<<1, 128, 0, stream>>>(bc_cnt, bc_base, bc_cursor, nbc, E);
    partition_kernel<<<(E + PART_BATCH - 1) / PART_BATCH, 256, 0, stream>>>(
        ei, bc_cursor, part, E, nbc);
    bucket_degrees<<<nbc, 1024, 0, stream>>>(part, bc_base, gdeg, N);
    int nb = (N + 1023) / 1024;
    scanA_kernel<<<nb, 256, 0, stream>>>(gdeg, rowptr, bsum, N);
    scanB_kernel<<<1, 1024, 0, stream>>>(bsum, nb);
    scanC_kernel<<<nb, 256, 0, stream>>>(rowptr, bsum, N, E);
    bucket_fill<<<nbc, 1024, 0, stream>>>(part, bc_base, rowptr, col, N);

    for (int l = 0; l < NLAYERS; l++) {
        agg_kernel<<<(N + 1) / 2, 128, 0, stream>>>(h, rowptr, col, eps, l, z, N);
        mlp_fused_kernel<<<(N + 63) / 64, 256, 0, stream>>>(
            z, W1F + (size_t)l * H * H2, W2F + (size_t)l * H * H2,
            sc1 + l * H2, sh1 + l * H2, sc2 + l * H, sh2 + l * H, h, N);
    }
    pool_kernel<<<G, 256, 0, stream>>>(h, batch, (float*)d_out, N, G);
}

// Round 12
// 844.049 us; speedup vs baseline: 1.3909x; 1.0107x over previous
//
#include <hip/hip_runtime.h>
#include <stdint.h>

#define H 128
#define H2 256
#define NLAYERS 4
#define BN_EPS 1e-5f

// CSR bucketing
#define BSHIFT 10
#define NPB 1024
#define NBC 98
#define PART_BATCH 2048
#define EPT 8

typedef __attribute__((ext_vector_type(4))) float f32x4;
typedef __attribute__((ext_vector_type(8))) short bhalf8;

__device__ __forceinline__ float bf2f(unsigned short u) {
    union { unsigned int i; float f; } v;
    v.i = ((unsigned int)u) << 16;
    return v.f;
}
__device__ __forceinline__ unsigned short f2bf(float f) {
    union { float f; unsigned int i; } v;
    v.f = f;
    unsigned int b = v.i + 0x7FFFu + ((v.i >> 16) & 1u);
    return (unsigned short)(b >> 16);
}
__device__ __forceinline__ float relu_bn(float a, float sc, float sh) {
    float v = a * sc + sh;
    return v > 0.f ? v : 0.f;
}

// ---------------- embedding: h = x @ Wemb + bemb  (bf16 out) ----------------
__global__ __launch_bounds__(256) void embed_kernel(
    const float* __restrict__ x, const float* __restrict__ Wemb,
    const float* __restrict__ bemb, unsigned short* __restrict__ h, int N) {
    int n = blockIdx.x * 2 + (threadIdx.x >> 7);
    int f = threadIdx.x & 127;
    if (n >= N) return;
    const float* xr = x + (size_t)n * 9;
    float acc = bemb[f];
#pragma unroll
    for (int k = 0; k < 9; k++) acc += xr[k] * Wemb[k * H + f];
    h[(size_t)n * H + f] = f2bf(acc);
}

// ---------------- BN param fold ----------------
__global__ void prep_params(
    const float* __restrict__ b1, const float* __restrict__ g1, const float* __restrict__ be1,
    const float* __restrict__ m1, const float* __restrict__ v1,
    const float* __restrict__ b2, const float* __restrict__ g2, const float* __restrict__ be2,
    const float* __restrict__ m2, const float* __restrict__ v2,
    float* __restrict__ sc1, float* __restrict__ sh1,
    float* __restrict__ sc2, float* __restrict__ sh2) {
    int t = threadIdx.x;  // 1024 threads
    if (t < NLAYERS * H2) {
        float s = g1[t] * rsqrtf(v1[t] + BN_EPS);
        sc1[t] = s;
        sh1[t] = (b1[t] - m1[t]) * s + be1[t];
    }
    if (t < NLAYERS * H) {
        float s = g2[t] * rsqrtf(v2[t] + BN_EPS);
        sc2[t] = s;
        sh2[t] = (b2[t] - m2[t]) * s + be2[t];
    }
}

// ---------------- weight fragment-order pack + bf16 convert ----------------
// W1F: idx = ((((l*16 + c16)*4 + ks)*64 + lane)*8 + e)
// W2F: idx = ((((l*8 + c16)*8 + ks)*64 + lane)*8 + e)
// c = c16*16 + (lane&15); k = ks*32 + (lane>>4)*8 + e
__global__ __launch_bounds__(256) void prep_weights(
    const float* __restrict__ W1, const float* __restrict__ W2,
    unsigned short* __restrict__ W1F, unsigned short* __restrict__ W2F) {
    int idx = blockIdx.x * 256 + threadIdx.x;
    if (idx >= NLAYERS * H * H2) return;
    {
        int e = idx & 7;
        int lane = (idx >> 3) & 63;
        int ks = (idx >> 9) & 3;
        int c16 = (idx >> 11) & 15;
        int l = idx >> 15;
        int c = c16 * 16 + (lane & 15);
        int k = ks * 32 + (lane >> 4) * 8 + e;
        W1F[idx] = f2bf(W1[((size_t)l * H + k) * H2 + c]);
    }
    {
        int e = idx & 7;
        int lane = (idx >> 3) & 63;
        int ks = (idx >> 9) & 7;
        int c16 = (idx >> 12) & 7;
        int l = idx >> 15;
        int c = c16 * 16 + (lane & 15);
        int k = ks * 32 + (lane >> 4) * 8 + e;
        W2F[idx] = f2bf(W2[((size_t)l * H2 + k) * H + c]);
    }
}

// ---------------- CSR build (bucketed; part packed: src<<10 | dst_local) ----
__global__ __launch_bounds__(256) void hist_coarse(const int* __restrict__ ei,
                                                   unsigned* __restrict__ bc_cnt,
                                                   int E, int nbc) {
    __shared__ unsigned lh[NBC];
    for (int i = threadIdx.x; i < nbc; i += 256) lh[i] = 0;
    __syncthreads();
    for (int e = blockIdx.x * 256 + threadIdx.x; e < E; e += gridDim.x * 256)
        atomicAdd(&lh[(unsigned)ei[E + e] >> BSHIFT], 1u);
    __syncthreads();
    for (int i = threadIdx.x; i < nbc; i += 256)
        if (lh[i]) atomicAdd(&bc_cnt[i], lh[i]);
}

__global__ __launch_bounds__(128) void scan_coarse(const unsigned* __restrict__ bc_cnt,
                                                   unsigned* __restrict__ bc_base,
                                                   unsigned* __restrict__ bc_cursor,
                                                   int nbc, int E) {
    __shared__ unsigned sd[128];
    int t = threadIdx.x;
    unsigned v = (t < nbc) ? bc_cnt[t] : 0u;
    sd[t] = v;
    __syncthreads();
    for (int off = 1; off < 128; off <<= 1) {
        unsigned xv = (t >= off) ? sd[t - off] : 0u;
        __syncthreads();
        sd[t] += xv;
        __syncthreads();
    }
    unsigned excl = sd[t] - v;
    if (t < nbc) {
        bc_base[t] = excl;
        bc_cursor[t] = excl;
    }
    if (t == 0) bc_base[nbc] = (unsigned)E;
}

__global__ __launch_bounds__(256) void partition_kernel(const int* __restrict__ ei,
                                                        unsigned* __restrict__ bc_cursor,
                                                        unsigned* __restrict__ part,
                                                        int E, int nbc) {
    __shared__ unsigned lh[NBC];
    __shared__ unsigned lb[NBC];
    for (int i = threadIdx.x; i < nbc; i += 256) lh[i] = 0;
    __syncthreads();
    int base = blockIdx.x * PART_BATCH;
    int s[EPT], d[EPT];
    unsigned rank[EPT];
    int bk[EPT];
#pragma unroll
    for (int k = 0; k < EPT; k++) {
        int e = base + k * 256 + threadIdx.x;
        if (e < E) {
            s[k] = ei[e];
            d[k] = ei[E + e];
            bk[k] = (unsigned)d[k] >> BSHIFT;
            rank[k] = atomicAdd(&lh[bk[k]], 1u);
        } else bk[k] = -1;
    }
    __syncthreads();
    for (int i = threadIdx.x; i < nbc; i += 256)
        lb[i] = lh[i] ? atomicAdd(&bc_cursor[i], lh[i]) : 0u;
    __syncthreads();
#pragma unroll
    for (int k = 0; k < EPT; k++) {
        if (bk[k] >= 0) {
            unsigned p = lb[bk[k]] + rank[k];
            part[p] = ((unsigned)s[k] << BSHIFT) | ((unsigned)d[k] & (NPB - 1));
        }
    }
}

__global__ __launch_bounds__(1024) void bucket_degrees(const unsigned* __restrict__ part,
                                                       const unsigned* __restrict__ bc_base,
                                                       unsigned* __restrict__ gdeg, int N) {
    __shared__ unsigned deg[NPB];
    int b = blockIdx.x;
    deg[threadIdx.x] = 0;
    __syncthreads();
    unsigned r0 = bc_base[b], r1 = bc_base[b + 1];
    for (unsigned i = r0 + threadIdx.x; i < r1; i += 1024)
        atomicAdd(&deg[part[i] & (NPB - 1)], 1u);
    __syncthreads();
    int node = (b << BSHIFT) + threadIdx.x;
    if (node < N) gdeg[node] = deg[threadIdx.x];
}

__global__ __launch_bounds__(256) void scanA_kernel(const unsigned* __restrict__ deg,
                                                    unsigned* __restrict__ rowptr,
                                                    unsigned* __restrict__ bsum, int N) {
    __shared__ unsigned sd[256];
    int tid = threadIdx.x;
    int base = blockIdx.x * 1024 + tid * 4;
    unsigned v[4];
    unsigned s = 0;
#pragma unroll
    for (int j = 0; j < 4; j++) {
        v[j] = (base + j < N) ? deg[base + j] : 0u;
        s += v[j];
    }
    sd[tid] = s;
    __syncthreads();
    for (int off = 1; off < 256; off <<= 1) {
        unsigned xv = (tid >= off) ? sd[tid - off] : 0u;
        __syncthreads();
        sd[tid] += xv;
        __syncthreads();
    }
    unsigned excl = sd[tid] - s;
#pragma unroll
    for (int j = 0; j < 4; j++) {
        if (base + j < N) rowptr[base + j] = excl;
        excl += v[j];
    }
    if (tid == 255) bsum[blockIdx.x] = sd[255];
}

__global__ __launch_bounds__(1024) void scanB_kernel(unsigned* __restrict__ bsum, int nb) {
    __shared__ unsigned sd[1024];
    int t = threadIdx.x;
    unsigned s = (t < nb) ? bsum[t] : 0u;
    sd[t] = s;
    __syncthreads();
    for (int off = 1; off < 1024; off <<= 1) {
        unsigned xv = (t >= off) ? sd[t - off] : 0u;
        __syncthreads();
        sd[t] += xv;
        __syncthreads();
    }
    if (t < nb) bsum[t] = sd[t] - s;
}

__global__ __launch_bounds__(256) void scanC_kernel(unsigned* __restrict__ rowptr,
                                                    const unsigned* __restrict__ bsum,
                                                    int N, int E) {
    int base = blockIdx.x * 1024 + threadIdx.x * 4;
    unsigned off = bsum[blockIdx.x];
#pragma unroll
    for (int j = 0; j < 4; j++) {
        int i = base + j;
        if (i < N) rowptr[i] += off;
    }
    if (blockIdx.x == 0 && threadIdx.x == 0) rowptr[N] = (unsigned)E;
}

__global__ __launch_bounds__(1024) void bucket_fill(const unsigned* __restrict__ part,
                                                    const unsigned* __restrict__ bc_base,
                                                    const unsigned* __restrict__ rowptr,
                                                    unsigned* __restrict__ col, int N) {
    __shared__ unsigned cur[NPB];
    int b = blockIdx.x;
    int node = (b << BSHIFT) + threadIdx.x;
    cur[threadIdx.x] = (node < N) ? rowptr[node] : 0u;
    __syncthreads();
    unsigned r0 = bc_base[b], r1 = bc_base[b + 1];
    for (unsigned i = r0 + threadIdx.x; i < r1; i += 1024) {
        unsigned e = part[i];
        unsigned p = atomicAdd(&cur[e & (NPB - 1)], 1u);
        col[p] = e >> BSHIFT;
    }
}

// ---------------- aggregation: z = (1+eps)*h + sum_{neigh} h ----------------
// 2 nodes per 128-thread block; 8 neighbor rows in flight (known-good config).
__global__ __launch_bounds__(128) void agg_kernel(
    const unsigned short* __restrict__ h, const unsigned* __restrict__ rowptr,
    const unsigned* __restrict__ col, const float* __restrict__ eps, int layer,
    unsigned short* __restrict__ z, int N) {
    int n = blockIdx.x * 2 + (threadIdx.x >> 6);
    if (n >= N) return;
    int lane = threadIdx.x & 63;
    int chunk = lane & 15;
    int sub = lane >> 4;
    unsigned r0 = rowptr[n], r1 = rowptr[n + 1];
    float acc0[8], acc1[8];
#pragma unroll
    for (int k = 0; k < 8; k++) { acc0[k] = 0.f; acc1[k] = 0.f; }
    unsigned j = r0 + sub;
    for (; j + 4 < r1; j += 8) {
        unsigned c0 = col[j], c1 = col[j + 4];
        bhalf8 v0 = *(const bhalf8*)&h[(size_t)c0 * H + chunk * 8];
        bhalf8 v1 = *(const bhalf8*)&h[(size_t)c1 * H + chunk * 8];
#pragma unroll
        for (int k = 0; k < 8; k++) {
            acc0[k] += bf2f((unsigned short)v0[k]);
            acc1[k] += bf2f((unsigned short)v1[k]);
        }
    }
    if (j < r1) {
        unsigned c0 = col[j];
        bhalf8 v0 = *(const bhalf8*)&h[(size_t)c0 * H + chunk * 8];
#pragma unroll
        for (int k = 0; k < 8; k++) acc0[k] += bf2f((unsigned short)v0[k]);
    }
#pragma unroll
    for (int k = 0; k < 8; k++) {
        acc0[k] += acc1[k];
        acc0[k] += __shfl_xor(acc0[k], 16, 64);
        acc0[k] += __shfl_xor(acc0[k], 32, 64);
    }
    if (sub == 0) {
        float e = 1.0f + eps[layer];
        bhalf8 hv = *(const bhalf8*)&h[(size_t)n * H + chunk * 8];
        bhalf8 o;
#pragma unroll
        for (int k = 0; k < 8; k++)
            o[k] = (short)f2bf(e * bf2f((unsigned short)hv[k]) + acc0[k]);
        *(bhalf8*)&z[(size_t)n * H + chunk * 8] = o;
    }
}

// ---------------- fused MLP: h = relu(bn2(relu(bn1(z@W1))@W2)) ----------------
// Operand-SWAPPED MFMA (A=weights, B=activations): D[c][r] lane layout gives
// each lane row r=lane&15 and 4 CONSECUTIVE cols -> packed b64 LDS writes
// (16 vs 64 stores) and dwordx2 global h writes (8 vs 32 stores).
#define LDP 264
__global__ __launch_bounds__(256) void mlp_fused_kernel(
    const unsigned short* __restrict__ z, const unsigned short* __restrict__ W1F,
    const unsigned short* __restrict__ W2F,
    const float* __restrict__ sc1, const float* __restrict__ sh1,
    const float* __restrict__ sc2, const float* __restrict__ sh2,
    unsigned short* __restrict__ h, int N) {
    __shared__ unsigned short tl[64 * LDP];
    int wave = threadIdx.x >> 6, lane = threadIdx.x & 63;
    int rtile = blockIdx.x * 64;
    int rlane = lane & 15;
    int kq = lane >> 4;
    int kg = kq * 8;
    int arow[4];
#pragma unroll
    for (int rb = 0; rb < 4; rb++) {
        int r = rtile + rb * 16 + rlane;
        arow[rb] = r < N ? r : N - 1;
    }
    f32x4 zero = {0.f, 0.f, 0.f, 0.f};
    // ---- stage 1: t = relu(bn1(z @ W1)), D = (W1^T x z^T) fragments ----
    {
        f32x4 acc[4][4];
#pragma unroll
        for (int rb = 0; rb < 4; rb++)
#pragma unroll
            for (int cb = 0; cb < 4; cb++) acc[rb][cb] = zero;
#pragma unroll
        for (int ks = 0; ks < 4; ks++) {
            bhalf8 a[4], b[4];
#pragma unroll
            for (int rb = 0; rb < 4; rb++)
                a[rb] = *(const bhalf8*)&z[(size_t)arow[rb] * H + ks * 32 + kg];
#pragma unroll
            for (int cb = 0; cb < 4; cb++)
                b[cb] = *(const bhalf8*)&W1F[((size_t)((wave * 4 + cb) * 4 + ks) * 64 + lane) * 8];
#pragma unroll
            for (int rb = 0; rb < 4; rb++)
#pragma unroll
                for (int cb = 0; cb < 4; cb++)
                    acc[rb][cb] = __builtin_amdgcn_mfma_f32_16x16x32_bf16(b[cb], a[rb], acc[rb][cb], 0, 0, 0);
        }
#pragma unroll
        for (int cb = 0; cb < 4; cb++) {
            int c0 = wave * 64 + cb * 16 + kq * 4;
            f32x4 sc = *(const f32x4*)&sc1[c0];
            f32x4 sh = *(const f32x4*)&sh1[c0];
#pragma unroll
            for (int rb = 0; rb < 4; rb++) {
                int rl = rb * 16 + rlane;
                unsigned w0 = (unsigned)f2bf(relu_bn(acc[rb][cb][0], sc[0], sh[0])) |
                              ((unsigned)f2bf(relu_bn(acc[rb][cb][1], sc[1], sh[1])) << 16);
                unsigned w1 = (unsigned)f2bf(relu_bn(acc[rb][cb][2], sc[2], sh[2])) |
                              ((unsigned)f2bf(relu_bn(acc[rb][cb][3], sc[3], sh[3])) << 16);
                uint2 w;
                w.x = w0; w.y = w1;
                *(uint2*)&tl[rl * LDP + c0] = w;
            }
        }
    }
    __syncthreads();
    // ---- stage 2: h = relu(bn2(t @ W2)), D = (W2^T x t^T) fragments ----
    {
        f32x4 acc[4][2];
#pragma unroll
        for (int rb = 0; rb < 4; rb++)
#pragma unroll
            for (int cb = 0; cb < 2; cb++) acc[rb][cb] = zero;
#pragma unroll
        for (int ks = 0; ks < 8; ks++) {
            bhalf8 a[4], b[2];
#pragma unroll
            for (int rb = 0; rb < 4; rb++)
                a[rb] = *(const bhalf8*)&tl[(rb * 16 + rlane) * LDP + ks * 32 + kg];
#pragma unroll
            for (int cb = 0; cb < 2; cb++)
                b[cb] = *(const bhalf8*)&W2F[((size_t)((wave * 2 + cb) * 8 + ks) * 64 + lane) * 8];
#pragma unroll
            for (int rb = 0; rb < 4; rb++)
#pragma unroll
                for (int cb = 0; cb < 2; cb++)
                    acc[rb][cb] = __builtin_amdgcn_mfma_f32_16x16x32_bf16(b[cb], a[rb], acc[rb][cb], 0, 0, 0);
        }
#pragma unroll
        for (int cb = 0; cb < 2; cb++) {
            int c0 = wave * 32 + cb * 16 + kq * 4;
            f32x4 sc = *(const f32x4*)&sc2[c0];
            f32x4 sh = *(const f32x4*)&sh2[c0];
#pragma unroll
            for (int rb = 0; rb < 4; rb++) {
                int row = rtile + rb * 16 + rlane;
                if (row < N) {
                    unsigned w0 = (unsigned)f2bf(relu_bn(acc[rb][cb][0], sc[0], sh[0])) |
                                  ((unsigned)f2bf(relu_bn(acc[rb][cb][1], sc[1], sh[1])) << 16);
                    unsigned w1 = (unsigned)f2bf(relu_bn(acc[rb][cb][2], sc[2], sh[2])) |
                                  ((unsigned)f2bf(relu_bn(acc[rb][cb][3], sc[3], sh[3])) << 16);
                    uint2 w;
                    w.x = w0; w.y = w1;
                    *(uint2*)&h[(size_t)row * H + c0] = w;
                }
            }
        }
    }
}

// ---------------- global mean pool (8 rows in flight per graph) ----------------
__global__ __launch_bounds__(256) void pool_kernel(
    const unsigned short* __restrict__ h, const int* __restrict__ batch,
    float* __restrict__ out, int N, int G) {
    __shared__ float sacc[2][128];
    __shared__ int se[2];
    int g = blockIdx.x;
    if (threadIdx.x == 0) {
        int lo = 0, hi = N;
        while (lo < hi) {
            int mid = (lo + hi) >> 1;
            if (batch[mid] < g) lo = mid + 1; else hi = mid;
        }
        se[0] = lo;
        hi = N;
        while (lo < hi) {
            int mid = (lo + hi) >> 1;
            if (batch[mid] < g + 1) lo = mid + 1; else hi = mid;
        }
        se[1] = lo;
    }
    __syncthreads();
    int s = se[0], e = se[1];
    int f = threadIdx.x & 127;
    int half = threadIdx.x >> 7;
    float a0 = 0.f, a1 = 0.f, a2 = 0.f, a3 = 0.f;
    int r = s + half;
    for (; r + 6 < e; r += 8) {
        a0 += bf2f(h[(size_t)r * H + f]);
        a1 += bf2f(h[(size_t)(r + 2) * H + f]);
        a2 += bf2f(h[(size_t)(r + 4) * H + f]);
        a3 += bf2f(h[(size_t)(r + 6) * H + f]);
    }
    for (; r < e; r += 2) a0 += bf2f(h[(size_t)r * H + f]);
    sacc[half][f] = (a0 + a1) + (a2 + a3);
    __syncthreads();
    if (half == 0) {
        int cnt = e - s;
        float v = sacc[0][f] + sacc[1][f];
        out[(size_t)g * H + f] = cnt > 0 ? v / (float)cnt : 0.f;
    }
}

// ---------------- launch ----------------
extern "C" void kernel_launch(void* const* d_in, const int* in_sizes, int n_in,
                              void* d_out, int out_size, void* d_ws, size_t ws_size,
                              hipStream_t stream) {
    const float* x     = (const float*)d_in[0];
    const int*   ei    = (const int*)d_in[1];
    const int*   batch = (const int*)d_in[2];
    const float* Wemb  = (const float*)d_in[3];
    const float* bemb  = (const float*)d_in[4];
    const float* eps   = (const float*)d_in[5];
    const float* W1    = (const float*)d_in[6];
    const float* b1    = (const float*)d_in[7];
    const float* g1    = (const float*)d_in[8];
    const float* be1   = (const float*)d_in[9];
    const float* m1    = (const float*)d_in[10];
    const float* v1    = (const float*)d_in[11];
    const float* W2    = (const float*)d_in[12];
    const float* b2    = (const float*)d_in[13];
    const float* g2    = (const float*)d_in[14];
    const float* be2   = (const float*)d_in[15];
    const float* m2    = (const float*)d_in[16];
    const float* v2    = (const float*)d_in[17];

    int N = in_sizes[0] / 9;
    int E = in_sizes[1] / 2;
    int G = out_size / H;
    int nbc = (N + NPB - 1) >> BSHIFT;

    char* p = (char*)d_ws;
    auto alloc = [&](size_t bytes) -> char* {
        char* r = p;
        p += (bytes + 255) & ~(size_t)255;
        return r;
    };
    unsigned short* h   = (unsigned short*)alloc((size_t)N * H * 2);
    unsigned short* z   = (unsigned short*)alloc((size_t)N * H * 2);
    unsigned*       part = (unsigned*)alloc((size_t)E * 4);
    unsigned*       rowptr = (unsigned*)alloc((size_t)(N + 1) * 4);
    unsigned*       gdeg   = (unsigned*)alloc((size_t)N * 4);
    unsigned*       bsum   = (unsigned*)alloc(1024 * 4);
    unsigned*       col    = (unsigned*)alloc((size_t)E * 4);
    unsigned short* W1F = (unsigned short*)alloc((size_t)NLAYERS * H * H2 * 2);
    unsigned short* W2F = (unsigned short*)alloc((size_t)NLAYERS * H * H2 * 2);
    float* sc1 = (float*)alloc(NLAYERS * H2 * 4);
    float* sh1 = (float*)alloc(NLAYERS * H2 * 4);
    float* sc2 = (float*)alloc(NLAYERS * H * 4);
    float* sh2 = (float*)alloc(NLAYERS * H * 4);
    unsigned* bc_cnt    = (unsigned*)alloc((NBC + 2) * 4);
    unsigned* bc_base   = (unsigned*)alloc((NBC + 2) * 4);
    unsigned* bc_cursor = (unsigned*)alloc((NBC + 2) * 4);

    hipMemsetAsync(bc_cnt, 0, (NBC + 2) * 4, stream);
    prep_params<<<1, 1024, 0, stream>>>(b1, g1, be1, m1, v1, b2, g2, be2, m2, v2,
                                        sc1, sh1, sc2, sh2);
    prep_weights<<<(NLAYERS * H * H2 + 255) / 256, 256, 0, stream>>>(W1, W2, W1F, W2F);
    embed_kernel<<<(N + 1) / 2, 256, 0, stream>>>(x, Wemb, bemb, h, N);

    // CSR build
    hist_coarse<<<512, 256, 0, stream>>>(ei, bc_cnt, E, nbc);
    scan_coarse<<<1, 128, 0, stream>>>(bc_cnt, bc_base, bc_cursor, nbc, E);
    partition_kernel<<<(E + PART_BATCH - 1) / PART_BATCH, 256, 0, stream>>>(
        ei, bc_cursor, part, E, nbc);
    bucket_degrees<<<nbc, 1024, 0, stream>>>(part, bc_base, gdeg, N);
    int nb = (N + 1023) / 1024;
    scanA_kernel<<<nb, 256, 0, stream>>>(gdeg, rowptr, bsum, N);
    scanB_kernel<<<1, 1024, 0, stream>>>(bsum, nb);
    scanC_kernel<<<nb, 256, 0, stream>>>(rowptr, bsum, N, E);
    bucket_fill<<<nbc, 1024, 0, stream>>>(part, bc_base, rowptr, col, N);

    for (int l = 0; l < NLAYERS; l++) {
        agg_kernel<<<(N + 1) / 2, 128, 0, stream>>>(h, rowptr, col, eps, l, z, N);
        mlp_fused_kernel<<<(N + 63) / 64, 256, 0, stream>>>(
            z, W1F + (size_t)l * H * H2, W2F + (size_t)l * H * H2,
            sc1 + l * H2, sh1 + l * H2, sc2 + l * H, sh2 + l * H, h, N);
    }
    pool_kernel<<<G, 256, 0, stream>>>(h, batch, (float*)d_out, N, G);
}